// Round 5
// baseline (845.124 us; speedup 1.0000x reference)
//
#include <hip/hip_runtime.h>
#include <hip/hip_cooperative_groups.h>

namespace cg = cooperative_groups;

struct Params {
  const float *X, *E, *nbr;
  const float *embW, *embB, *boutW, *boutB;
  const float *qpW, *qpB, *kpW, *kpB, *qoW, *qoB, *koW, *koB;
  const float *bpW, *bpB, *bowW, *bowB;
  const float *qlnG, *qlnB, *klnG, *klnB;
  float *out;
  float *pkT;      // [4][512][256] all-layer transposed keys
  float *rareRow;  // [65536][128] rare-pair bias rows (own-block use only)
  float *clsDiff;  // [4][2][4] class-bias norms from the dedicated bias block
  float *rareDiff; // [256][256][16] rare-pair diffs (own-block use only)
};

__device__ __forceinline__ float mishf(float x) {
  float sp = (x > 20.f) ? x : log1pf(expf(x));
  return x * tanhf(sp);
}

// NOTE: must be a function, not a macro — a macro param named `w` would be
// substituted into `acc.w` by the preprocessor (round-4 compile failure).
__device__ __forceinline__ void fma4(float4& acc, float s, const float4& v) {
  acc.x = fmaf(s, v.x, acc.x);
  acc.y = fmaf(s, v.y, acc.y);
  acc.z = fmaf(s, v.z, acc.z);
  acc.w = fmaf(s, v.w, acc.w);
}

// Full bias pipe for one rare-pair row, one layer (own-block; barriers inside).
// Cold correctness path (no rare pairs in this data) — scalar loads are fine.
__device__ void rare_pipe(float* row, float* drow,
                          const float* __restrict__ Wp, const float* __restrict__ Bp,
                          const float* __restrict__ Wo, const float* __restrict__ Bo,
                          float* smW, float* smS, int t) {
  const int lane = t & 63, wave = t >> 6;
  if (t < 128) smS[t] = row[t];
  __syncthreads();
  { const int o = t & 511, kh = t >> 9;
    const float* Wc = Wp + (kh * 64) * 512 + o;
    const float* rc = smS + kh * 64;
    float a = (kh == 0) ? Bp[o] : 0.f;
    #pragma unroll 8
    for (int c = 0; c < 64; ++c) a = fmaf(rc[c], Wc[c * 512], a);
    smW[t] = a; }
  __syncthreads();
  if (t < 512) smS[128 + t] = smW[t] + smW[512 + t];
  __syncthreads();
  if (wave < 4) {
    float e1 = smS[128 + wave * 128 + lane], e2 = smS[128 + wave * 128 + 64 + lane];
    float s = e1 * e1 + e2 * e2;
    #pragma unroll
    for (int sh = 32; sh; sh >>= 1) s += __shfl_xor(s, sh);
    if (lane == 0) drow[wave] = sqrtf(s);
  }
  { const int c = t & 127, ch = t >> 7;
    const float* Woc = Wo + (ch * 64) * 128 + c;
    const float* bc = smS + 128 + ch * 64;
    float a = 0.f;
    #pragma unroll 8
    for (int o2 = 0; o2 < 64; ++o2) a = fmaf(bc[o2], Woc[o2 * 128], a);
    smW[t] = a; }
  __syncthreads();
  if (t < 128) {
    float a = Bo[t];
    #pragma unroll
    for (int j = 0; j < 8; ++j) a += smW[t + 128 * j];
    row[t] = mishf(a);
  }
  __syncthreads();
}

// 129 blocks x 1024 threads; ONE grid.sync. (Cooperative cap: 1 block/CU -> <=256.)
// Blocks 0..127: DUAL-crystal chains (n = 2b, 2b+1) jammed on one weight stream.
// Block 128: the n-independent class-bias chain.
// All hot GEMVs: float4 weight loads along O + explicit 8-deep load batches (MLP).
__global__ void __launch_bounds__(1024, 4) crakn(Params P) {
  cg::grid_group grid = cg::this_grid();
  const int b = blockIdx.x, t = threadIdx.x;
  const int lane = t & 63, wave = t >> 6;
  const int nA = 2 * b, nB = 2 * b + 1;

  // persistent
  __shared__ __align__(16) float smPQA[2048];         // pq all layers, crystal A
  __shared__ __align__(16) float smPQB[2048];         // crystal B
  __shared__ __align__(16) float smKrA[512], smKrB[512];
  __shared__ __align__(16) float smQA[64], smQB[64], smKqA[64], smKqB[64];
  __shared__ __align__(16) float smNbr[256];
  __shared__ int   smMapA[256], smMapB[256];  // -2 zero-class, -1 gen-class, >=0 rare
  __shared__ float smDiff[32];                // [layer][class][head]
  __shared__ __align__(16) float rowBuf[512]; // bias block: class rows; crystal: E staging
  __shared__ float smPredA, smPredB;
  __shared__ int   smIA[257], smIB[257];
  __shared__ float smDA[256], smDB[256];
  // scratch
  __shared__ __align__(16) float4 smP4A[1024];        // partials (crystal A / class z)
  __shared__ __align__(16) float4 smP4B[1024];        // partials (crystal B / class g)
  __shared__ __align__(16) float smW[1024], smB2[1024], smX2[1024], smY2[1024];
  __shared__ float smH[128];

  if (b == 128) {
    // ================= Dedicated class-bias chain =================
    if (t < 128) {
      float c = (float)t * (1.f / 127.f);
      rowBuf[t] = expf(-127.f * c * c);  // zero class (d == 0)
      rowBuf[128 + t] = 0.f;             // gen class (underflowed)
    }
    __syncthreads();
    for (int l = 0; l < 4; ++l) {
      const float* rowCur = rowBuf + (l & 1) * 256;
      float* rowNxt = rowBuf + ((l + 1) & 1) * 256;
      // bias1 partials: thread = (kc in 0..7) x (o4 in 0..127); 16 K each
      { const int o4 = t & 127, kc = t >> 7;
        const float4* Wf = (const float4*)(P.bpW + (size_t)l * 65536) + (size_t)(kc * 16) * 128 + o4;
        float4 az = {0.f,0.f,0.f,0.f}, ag = {0.f,0.f,0.f,0.f};
        #pragma unroll
        for (int half = 0; half < 2; ++half) {
          float4 wv[8];
          #pragma unroll
          for (int j = 0; j < 8; ++j) wv[j] = Wf[(half * 8 + j) * 128];
          #pragma unroll
          for (int j = 0; j < 8; ++j) {
            const int r = kc * 16 + half * 8 + j;
            float z = rowCur[r], g2 = rowCur[128 + r];
            fma4(az, z, wv[j]); fma4(ag, g2, wv[j]);
          }
        }
        smP4A[t] = az; smP4B[t] = ag; }   // idx = kc*128 + o4
      __syncthreads();
      if (t < 512) {
        const float* pa = (const float*)smP4A;
        const float* pb = (const float*)smP4B;
        float bp = P.bpB[l * 512 + t];
        float z = bp, g2 = bp;
        #pragma unroll
        for (int kc = 0; kc < 8; ++kc) { z += pa[kc * 512 + t]; g2 += pb[kc * 512 + t]; }
        smW[t] = z; smB2[t] = g2;
      }
      __syncthreads();
      if (wave < 8) {                     // per-head norms -> global clsDiff
        const int cls = wave >> 2, h = wave & 3;
        const float* arr = cls ? smB2 : smW;
        float e1 = arr[h * 128 + lane], e2 = arr[h * 128 + 64 + lane];
        float s = e1 * e1 + e2 * e2;
        #pragma unroll
        for (int sh = 32; sh; sh >>= 1) s += __shfl_xor(s, sh);
        if (lane == 0) P.clsDiff[(l * 2 + cls) * 4 + h] = sqrtf(s);
      }
      if (l < 3) {
        // bias2 partials: thread = (kc in 0..31) x (o4 in 0..31); 16 K each
        { const int o4 = t & 31, kc = t >> 5;
          const float4* Wf = (const float4*)(P.bowW + (size_t)l * 65536) + (size_t)(kc * 16) * 32 + o4;
          float4 az = {0.f,0.f,0.f,0.f}, ag = {0.f,0.f,0.f,0.f};
          #pragma unroll
          for (int half = 0; half < 2; ++half) {
            float4 wv[8];
            #pragma unroll
            for (int j = 0; j < 8; ++j) wv[j] = Wf[(half * 8 + j) * 32];
            #pragma unroll
            for (int j = 0; j < 8; ++j) {
              const int r = kc * 16 + half * 8 + j;
              float z = smW[r], g2 = smB2[r];
              fma4(az, z, wv[j]); fma4(ag, g2, wv[j]);
            }
          }
          smP4A[t] = az; smP4B[t] = ag; }  // idx = kc*32 + o4
        __syncthreads();
        if (t < 128) {
          const float* pa = (const float*)smP4A;
          const float* pb = (const float*)smP4B;
          float bo = P.bowB[l * 128 + t];
          float sz = 0.f, sg = 0.f;
          #pragma unroll
          for (int kc = 0; kc < 32; ++kc) { sz += pa[kc * 128 + t]; sg += pb[kc * 128 + t]; }
          rowNxt[t] = mishf(sz + bo);
          rowNxt[128 + t] = mishf(sg + bo);
        }
        __syncthreads();
      }
    }
  } else {
    // ================= Phase A: embed / pred0 / distances (dual) =================
    if (t < 256) {
      smX2[t] = P.X[(size_t)nA * 256 + t];
      smY2[t] = P.X[(size_t)nB * 256 + t];
      smNbr[t] = P.nbr[t];
    }
    if (t == 0) { smIA[256] = 0; smIB[256] = 0; }
    __syncthreads();
    { const int d = t & 63, ch = t >> 6;
      const float* W = P.embW + (ch * 16) * 64 + d;
      const float* xrA = smX2 + ch * 16;
      const float* xrB = smY2 + ch * 16;
      float aA = 0.f, aB = 0.f;
      #pragma unroll
      for (int f = 0; f < 16; ++f) {
        float w = W[f * 64];
        aA = fmaf(xrA[f], w, aA);
        aB = fmaf(xrB[f], w, aB);
      }
      smW[t] = aA; smB2[t] = aB; }
    { float pp = 0.f;
      if (t < 256) pp = smX2[t] * P.boutW[t];
      else if (t < 512) pp = smY2[t - 256] * P.boutW[t - 256];
      #pragma unroll
      for (int s = 32; s; s >>= 1) pp += __shfl_xor(pp, s);
      if (t < 512 && lane == 0) smH[wave] = pp; }   // waves 0..3 A, 4..7 B
    __syncthreads();
    if (t < 64) {
      float ndA = P.embB[t], ndB = P.embB[t];
      #pragma unroll
      for (int j = 0; j < 16; ++j) { ndA += smW[t + 64 * j]; ndB += smB2[t + 64 * j]; }
      smQA[t] = ndA; smKqA[t] = ndA;
      smQB[t] = ndB; smKqB[t] = ndB;
    }
    if (t == 0) {
      smPredA = smH[0] + smH[1] + smH[2] + smH[3] + P.boutB[0];
      smPredB = smH[4] + smH[5] + smH[6] + smH[7] + P.boutB[0];
    }
    if (t < 25) {
      ((float4*)rowBuf)[t]         = ((const float4*)(P.E + (size_t)nA * 100))[t];
      ((float4*)(rowBuf + 128))[t] = ((const float4*)(P.E + (size_t)nB * 100))[t];
    }
    __syncthreads();
    if (t < 512) {                      // distances: t<256 crystal A, else B
      const int m = t & 255, cr = t >> 8;
      const float4* em = (const float4*)(P.E + (size_t)m * 100);
      const float4* en = (const float4*)(cr ? (rowBuf + 128) : rowBuf);
      float sq = 0.f;
      #pragma unroll 5
      for (int jj = 0; jj < 25; ++jj) {
        float4 a = en[jj], c = em[jj];
        float dx = a.x - c.x, dy = a.y - c.y, dz = a.z - c.z, dw = a.w - c.w;
        sq += dx * dx + dy * dy + dz * dz + dw * dw;
      }
      float dd = (sq > 0.f) ? sqrtf(sq) : 0.f;
      // exp(-127*(d-c)^2) fp32-underflows to exactly 0 for d>=1.905.
      int mv;
      if (dd == 0.f) mv = -2;
      else if (dd < 1.905f) {
        int* sI = cr ? smIB : smIA;
        float* sD = cr ? smDB : smDA;
        int i = atomicAdd(&sI[256], 1);
        sI[i] = m; sD[i] = dd;
        mv = i;
      } else mv = -1;
      (cr ? smMapB : smMapA)[m] = mv;
    }
    __syncthreads();
    { int cntA = smIA[256]; if (cntA > 256) cntA = 256;   // rare RBF rows (none in data)
      for (int i = 0; i < cntA; ++i) if (t < 128) {
        float dd = smDA[i] - (float)t * (1.f / 127.f);
        P.rareRow[(size_t)(nA * 256 + i) * 128 + t] = expf(-127.f * dd * dd);
      }
      int cntB = smIB[256]; if (cntB > 256) cntB = 256;
      for (int i = 0; i < cntB; ++i) if (t < 128) {
        float dd = smDB[i] - (float)t * (1.f / 127.f);
        P.rareRow[(size_t)(nB * 256 + i) * 128 + t] = expf(-127.f * dd * dd);
      } }
    __syncthreads();

    // ============ Phase 1: dual q/k chains, float4 + batched loads ============
    for (int l = 0; l < 4; ++l) {
      // --- S0 partials: thread = (g, kc in 0..3, o4 in 0..127); 16 K each ---
      { const int g = t >> 9, u = t & 511;
        const int o4 = u & 127, kc = u >> 7;
        const float4* Wf = (const float4*)((g ? P.kpW : P.qpW) + (size_t)l * 32768)
                         + (size_t)(kc * 16) * 128 + o4;
        const float* xa = g ? smKqA : smQA;
        const float* xb = g ? smKqB : smQB;
        float4 aA = {0.f,0.f,0.f,0.f}, aB = {0.f,0.f,0.f,0.f};
        #pragma unroll
        for (int half = 0; half < 2; ++half) {
          float4 wv[8];
          #pragma unroll
          for (int j = 0; j < 8; ++j) wv[j] = Wf[(half * 8 + j) * 128];
          #pragma unroll
          for (int j = 0; j < 8; ++j) {
            const int r = kc * 16 + half * 8 + j;
            float x = xa[r], y = xb[r];
            fma4(aA, x, wv[j]); fma4(aB, y, wv[j]);
          }
        }
        smP4A[t] = aA; smP4B[t] = aB; }   // idx = g*512 + kc*128 + o4
      __syncthreads();
      // --- S0 reduce: output o per (g); write pq/pk + pkT ---
      { const int g = t >> 9, o = t & 511;
        const float* pa = (const float*)smP4A + g * 2048;
        const float* pb = (const float*)smP4B + g * 2048;
        float b0 = (g ? P.kpB : P.qpB)[l * 512 + o];
        float vA = b0 + pa[o] + pa[512 + o] + pa[1024 + o] + pa[1536 + o];
        float vB = b0 + pb[o] + pb[512 + o] + pb[1024 + o] + pb[1536 + o];
        if (g) {
          smKrA[o] = vA; smKrB[o] = vB;
          float2 st; st.x = vA; st.y = vB;
          *(float2*)(P.pkT + (size_t)l * 131072 + (size_t)o * 256 + nA) = st;
        } else { smPQA[l * 512 + o] = vA; smPQB[l * 512 + o] = vB; } }
      __syncthreads();
      if (l < 3) {
        // --- S2 partials: thread = (g, kc in 0..31, o4 in 0..15); 16 K each ---
        { const int g = t >> 9, u = t & 511;
          const int o4 = u & 15, kc = u >> 4;
          const float4* Wf = (const float4*)((g ? P.koW : P.qoW) + (size_t)l * 32768)
                           + (size_t)(kc * 16) * 16 + o4;
          const float* prA = g ? smKrA : (smPQA + l * 512);
          const float* prB = g ? smKrB : (smPQB + l * 512);
          float4 aA = {0.f,0.f,0.f,0.f}, aB = {0.f,0.f,0.f,0.f};
          #pragma unroll
          for (int half = 0; half < 2; ++half) {
            float4 wv[8];
            #pragma unroll
            for (int j = 0; j < 8; ++j) wv[j] = Wf[(half * 8 + j) * 16];
            #pragma unroll
            for (int j = 0; j < 8; ++j) {
              const int r = kc * 16 + half * 8 + j;
              const int pi = ((r & 3) << 7) | (r >> 2);
              float x = prA[pi], y = prB[pi];
              fma4(aA, x, wv[j]); fma4(aB, y, wv[j]);
            }
          }
          smP4A[t] = aA; smP4B[t] = aB; }  // idx = g*512 + kc*16 + o4
        __syncthreads();
        // --- S3: reduce + mish + LN (waves 0,1 / 8,9 handle A,B) ---
        { const int g = t >> 9, u = t & 511;
          if (u < 128) {
            const int cr = u >> 6, uu = u & 63;
            const float* src = (const float*)(cr ? smP4B : smP4A) + g * 2048;
            float acc = (g ? P.koB : P.qoB)[l * 64 + uu];
            #pragma unroll
            for (int kc = 0; kc < 32; ++kc) acc += src[kc * 64 + uu];
            float* x = g ? (cr ? smKqB : smKqA) : (cr ? smQB : smQA);
            float xv = x[uu] + mishf(acc);
            float mean = xv;
            #pragma unroll
            for (int s = 32; s; s >>= 1) mean += __shfl_xor(mean, s);
            mean *= (1.f / 64.f);
            float dv = xv - mean, var = dv * dv;
            #pragma unroll
            for (int s = 32; s; s >>= 1) var += __shfl_xor(var, s);
            var *= (1.f / 64.f);
            const float* G  = (g ? P.klnG : P.qlnG) + l * 64;
            const float* Bb = (g ? P.klnB : P.qlnB) + l * 64;
            x[uu] = dv * rsqrtf(var + 1e-5f) * G[uu] + Bb[uu];
          } }
        __syncthreads();
      }
      // rare-pair pipes for layer l (own-block; none in this data)
      { int cntA = smIA[256]; if (cntA > 256) cntA = 256;
        int cntB = smIB[256]; if (cntB > 256) cntB = 256;
        if (cntA + cntB > 0) {
          __syncthreads();
          for (int i = 0; i < cntA; ++i)
            rare_pipe(P.rareRow + (size_t)(nA * 256 + i) * 128,
                      P.rareDiff + ((size_t)nA * 256 + i) * 16 + l * 4,
                      P.bpW + (size_t)l * 65536, P.bpB + l * 512,
                      P.bowW + (size_t)l * 65536, P.bowB + l * 128, smW, smX2, t);
          for (int i = 0; i < cntB; ++i)
            rare_pipe(P.rareRow + (size_t)(nB * 256 + i) * 128,
                      P.rareDiff + ((size_t)nB * 256 + i) * 16 + l * 4,
                      P.bpW + (size_t)l * 65536, P.bpB + l * 512,
                      P.bowW + (size_t)l * 65536, P.bowB + l * 128, smW, smX2, t);
        } }
    }
  }

  grid.sync();   // the ONLY grid-wide sync: pkT + clsDiff now visible
  if (b >= 128) return;

  // ====== Phase 2: ALL (layer, head) attention, both crystals jammed ======
  if (t < 32) smDiff[t] = P.clsDiff[t];
  __syncthreads();
  {
    const int l = t >> 8, h = (t >> 6) & 3, mq = lane;   // wave = (l,h), lane = mq
    const float* qvA = smPQA + l * 512 + h * 128;
    const float* qvB = smPQB + l * 512 + h * 128;
    const float4* pt4 = (const float4*)P.pkT + (size_t)l * 32768 + (size_t)h * 128 * 64 + mq;
    float4 dA = {0.f, 0.f, 0.f, 0.f}, dB = {0.f, 0.f, 0.f, 0.f};
    for (int jb = 0; jb < 16; ++jb) {
      float4 vb[8];
      #pragma unroll
      for (int j = 0; j < 8; ++j) vb[j] = pt4[(size_t)(jb * 8 + j) * 64];
      #pragma unroll
      for (int j = 0; j < 8; ++j) {
        float a = qvA[jb * 8 + j], c = qvB[jb * 8 + j];
        fma4(dA, a, vb[j]); fma4(dB, c, vb[j]);
      }
    }
    auto epi = [&](const float4& dot, const int* sMap, int nn, float* oH) {
      float dArr[4] = {dot.x, dot.y, dot.z, dot.w};
      float lg[4], nb[4];
      int self = -1;
      #pragma unroll
      for (int i = 0; i < 4; ++i) {
        const int m = mq * 4 + i;
        const int cls = sMap[m];
        float bd;
        if (cls >= 0) bd = P.rareDiff[((size_t)nn * 256 + cls) * 16 + l * 4 + h];
        else bd = smDiff[(l * 2 + (cls == -1 ? 1 : 0)) * 4 + h];
        lg[i] = dArr[i] * 0.08838834764831845f + bd;   // 1/sqrt(128)
        nb[i] = smNbr[m];
        if (m == nn) { self = i; nb[i] = 0.f; }
      }
      float wm = fmaxf(fmaxf(lg[0], lg[1]), fmaxf(lg[2], lg[3]));
      #pragma unroll
      for (int s = 32; s; s >>= 1) wm = fmaxf(wm, __shfl_xor(wm, s));
      float sA = 0.f, sB = 0.f, sD = 0.f;
      #pragma unroll
      for (int i = 0; i < 4; ++i) {
        float e = expf(lg[i] - wm);
        sD += e;
        sA = fmaf(e, nb[i], sA);
        if (i == self) sB = e;
      }
      #pragma unroll
      for (int s = 32; s; s >>= 1) {
        sA += __shfl_xor(sA, s); sB += __shfl_xor(sB, s); sD += __shfl_xor(sD, s);
      }
      if (lane == 0) { oH[wave] = sA; oH[16 + wave] = sB; oH[32 + wave] = sD; }
    };
    epi(dA, smMapA, nA, smH);
    epi(dB, smMapB, nB, smH + 48);
  }
  __syncthreads();
  if (t == 0 || t == 64) {              // serial pred chains (A on wave0, B on wave1)
    const float* H = (t == 0) ? smH : smH + 48;
    float p = (t == 0) ? smPredA : smPredB;
    #pragma unroll
    for (int l = 0; l < 4; ++l) {
      float np = 0.f;
      #pragma unroll
      for (int h = 0; h < 4; ++h) {
        const int w = l * 4 + h;
        np += 0.25f * ((H[w] + H[16 + w] * p) / H[32 + w]);
      }
      p = np;
    }
    P.out[(t == 0) ? nA : nB] = p;
  }
}

// ---------------------------------------------------------------------------
extern "C" void kernel_launch(void* const* d_in, const int* in_sizes, int n_in,
                              void* d_out, int out_size, void* d_ws, size_t ws_size,
                              hipStream_t stream) {
  char* p = (char*)d_ws;
  auto carve = [&](size_t bytes) -> void* {
    void* r = (void*)p;
    p += (bytes + 255) & ~(size_t)255;
    return r;
  };

  Params P;
  P.X     = (const float*)d_in[0];
  P.E     = (const float*)d_in[1];
  P.nbr   = (const float*)d_in[2];
  P.embW  = (const float*)d_in[3];
  P.embB  = (const float*)d_in[4];
  P.boutW = (const float*)d_in[5];
  P.boutB = (const float*)d_in[6];
  P.qpW   = (const float*)d_in[7];
  P.qpB   = (const float*)d_in[8];
  P.kpW   = (const float*)d_in[9];
  P.kpB   = (const float*)d_in[10];
  P.qoW   = (const float*)d_in[11];
  P.qoB   = (const float*)d_in[12];
  P.koW   = (const float*)d_in[13];
  P.koB   = (const float*)d_in[14];
  P.bpW   = (const float*)d_in[15];
  P.bpB   = (const float*)d_in[16];
  P.bowW  = (const float*)d_in[17];
  P.bowB  = (const float*)d_in[18];
  P.qlnG  = (const float*)d_in[19];
  P.qlnB  = (const float*)d_in[20];
  P.klnG  = (const float*)d_in[21];
  P.klnB  = (const float*)d_in[22];
  P.out   = (float*)d_out;

  P.pkT      = (float*)carve((size_t)4 * 512 * 256 * 4);
  P.rareRow  = (float*)carve((size_t)65536 * 128 * 4);
  P.clsDiff  = (float*)carve((size_t)32 * 4);
  P.rareDiff = (float*)carve((size_t)256 * 256 * 16 * 4);

  void* args[] = { &P };
  hipLaunchCooperativeKernel((const void*)crakn, dim3(129), dim3(1024), args, 0, stream);
}

// Round 6
// 837.167 us; speedup vs baseline: 1.0095x; 1.0095x over previous
//
#include <hip/hip_runtime.h>
#include <hip/hip_cooperative_groups.h>

namespace cg = cooperative_groups;

struct Params {
  const float *X, *E, *nbr;
  const float *embW, *embB, *boutW, *boutB;
  const float *qpW, *qpB, *kpW, *kpB, *qoW, *qoB, *koW, *koB;
  const float *bpW, *bpB, *bowW, *bowB;
  const float *qlnG, *qlnB, *klnG, *klnB;
  float *out;
  float *pkT;      // [4][512][256] all-layer transposed keys
  float *rareRow;  // [65536][128] rare-pair bias rows (own-block use only)
  float *clsDiff;  // [4][2][4] class-bias norms from the dedicated bias block
  float *rareDiff; // [256][256][16] rare-pair diffs (own-block use only)
};

__device__ __forceinline__ float mishf(float x) {
  float sp = (x > 20.f) ? x : log1pf(expf(x));
  return x * tanhf(sp);
}

// NOTE: function, not macro — a macro param named `w` gets substituted into
// `acc.w` by the preprocessor (round-4 compile failure).
__device__ __forceinline__ void fma4(float4& acc, float s, const float4& v) {
  acc.x = fmaf(s, v.x, acc.x);
  acc.y = fmaf(s, v.y, acc.y);
  acc.z = fmaf(s, v.z, acc.z);
  acc.w = fmaf(s, v.w, acc.w);
}

// Full bias pipe for one rare-pair row, one layer (own-block; barriers inside).
// Cold correctness path (no rare pairs in this data) — scalar loads are fine.
__device__ void rare_pipe(float* row, float* drow,
                          const float* __restrict__ Wp, const float* __restrict__ Bp,
                          const float* __restrict__ Wo, const float* __restrict__ Bo,
                          float* smW, float* smS, int t) {
  const int lane = t & 63, wave = t >> 6;
  if (t < 128) smS[t] = row[t];
  __syncthreads();
  { const int o = t & 511, kh = t >> 9;
    const float* Wc = Wp + (kh * 64) * 512 + o;
    const float* rc = smS + kh * 64;
    float a = (kh == 0) ? Bp[o] : 0.f;
    #pragma unroll 8
    for (int c = 0; c < 64; ++c) a = fmaf(rc[c], Wc[c * 512], a);
    smW[t] = a; }
  __syncthreads();
  if (t < 512) smS[128 + t] = smW[t] + smW[512 + t];
  __syncthreads();
  if (wave < 4) {
    float e1 = smS[128 + wave * 128 + lane], e2 = smS[128 + wave * 128 + 64 + lane];
    float s = e1 * e1 + e2 * e2;
    #pragma unroll
    for (int sh = 32; sh; sh >>= 1) s += __shfl_xor(s, sh);
    if (lane == 0) drow[wave] = sqrtf(s);
  }
  { const int c = t & 127, ch = t >> 7;
    const float* Woc = Wo + (ch * 64) * 128 + c;
    const float* bc = smS + 128 + ch * 64;
    float a = 0.f;
    #pragma unroll 8
    for (int o2 = 0; o2 < 64; ++o2) a = fmaf(bc[o2], Woc[o2 * 128], a);
    smW[t] = a; }
  __syncthreads();
  if (t < 128) {
    float a = Bo[t];
    #pragma unroll
    for (int j = 0; j < 8; ++j) a += smW[t + 128 * j];
    row[t] = mishf(a);
  }
  __syncthreads();
}

// 129 blocks x 1024 threads; ONE grid.sync. (Cooperative cap: 1 block/CU -> <=256.)
// Blocks 0..127: DUAL-crystal chains (n = 2b, 2b+1) jammed on one weight stream.
// Block 128: the n-independent class-bias chain.
// All hot GEMVs: float4 weight loads along O + explicit 8-deep load batches (MLP).
// amdgpu_waves_per_eu(4,4): our resident shape is exactly 4 waves/EU (one
// 1024-thread block per CU under cooperative launch). Without this, the LLVM
// heuristic budgets 64 VGPRs (8-waves/EU target) and SPILLS the 8-deep float4
// staging to scratch — round-5's 734MB FETCH / 392MB WRITE explosion.
__global__ void __launch_bounds__(1024)
__attribute__((amdgpu_waves_per_eu(4, 4)))
crakn(Params P) {
  cg::grid_group grid = cg::this_grid();
  const int b = blockIdx.x, t = threadIdx.x;
  const int lane = t & 63, wave = t >> 6;
  const int nA = 2 * b, nB = 2 * b + 1;

  // persistent
  __shared__ __align__(16) float smPQA[2048];         // pq all layers, crystal A
  __shared__ __align__(16) float smPQB[2048];         // crystal B
  __shared__ __align__(16) float smKrA[512], smKrB[512];
  __shared__ __align__(16) float smQA[64], smQB[64], smKqA[64], smKqB[64];
  __shared__ __align__(16) float smNbr[256];
  __shared__ int   smMapA[256], smMapB[256];  // -2 zero-class, -1 gen-class, >=0 rare
  __shared__ float smDiff[32];                // [layer][class][head]
  __shared__ __align__(16) float rowBuf[512]; // bias block: class rows; crystal: E staging
  __shared__ float smPredA, smPredB;
  __shared__ int   smIA[257], smIB[257];
  __shared__ float smDA[256], smDB[256];
  // scratch
  __shared__ __align__(16) float4 smP4A[1024];        // partials (crystal A / class z)
  __shared__ __align__(16) float4 smP4B[1024];        // partials (crystal B / class g)
  __shared__ __align__(16) float smW[1024], smB2[1024], smX2[1024], smY2[1024];
  __shared__ float smH[128];

  if (b == 128) {
    // ================= Dedicated class-bias chain =================
    if (t < 128) {
      float c = (float)t * (1.f / 127.f);
      rowBuf[t] = expf(-127.f * c * c);  // zero class (d == 0)
      rowBuf[128 + t] = 0.f;             // gen class (underflowed)
    }
    __syncthreads();
    for (int l = 0; l < 4; ++l) {
      const float* rowCur = rowBuf + (l & 1) * 256;
      float* rowNxt = rowBuf + ((l + 1) & 1) * 256;
      // bias1 partials: thread = (kc in 0..7) x (o4 in 0..127); 16 K each
      { const int o4 = t & 127, kc = t >> 7;
        const float4* Wf = (const float4*)(P.bpW + (size_t)l * 65536) + (size_t)(kc * 16) * 128 + o4;
        float4 az = {0.f,0.f,0.f,0.f}, ag = {0.f,0.f,0.f,0.f};
        #pragma unroll
        for (int half = 0; half < 2; ++half) {
          float4 wv[8];
          #pragma unroll
          for (int j = 0; j < 8; ++j) wv[j] = Wf[(half * 8 + j) * 128];
          #pragma unroll
          for (int j = 0; j < 8; ++j) {
            const int r = kc * 16 + half * 8 + j;
            float z = rowCur[r], g2 = rowCur[128 + r];
            fma4(az, z, wv[j]); fma4(ag, g2, wv[j]);
          }
        }
        smP4A[t] = az; smP4B[t] = ag; }   // idx = kc*128 + o4
      __syncthreads();
      if (t < 512) {
        const float* pa = (const float*)smP4A;
        const float* pb = (const float*)smP4B;
        float bp = P.bpB[l * 512 + t];
        float z = bp, g2 = bp;
        #pragma unroll
        for (int kc = 0; kc < 8; ++kc) { z += pa[kc * 512 + t]; g2 += pb[kc * 512 + t]; }
        smW[t] = z; smB2[t] = g2;
      }
      __syncthreads();
      if (wave < 8) {                     // per-head norms -> global clsDiff
        const int cls = wave >> 2, h = wave & 3;
        const float* arr = cls ? smB2 : smW;
        float e1 = arr[h * 128 + lane], e2 = arr[h * 128 + 64 + lane];
        float s = e1 * e1 + e2 * e2;
        #pragma unroll
        for (int sh = 32; sh; sh >>= 1) s += __shfl_xor(s, sh);
        if (lane == 0) P.clsDiff[(l * 2 + cls) * 4 + h] = sqrtf(s);
      }
      if (l < 3) {
        // bias2 partials: thread = (kc in 0..31) x (o4 in 0..31); 16 K each
        { const int o4 = t & 31, kc = t >> 5;
          const float4* Wf = (const float4*)(P.bowW + (size_t)l * 65536) + (size_t)(kc * 16) * 32 + o4;
          float4 az = {0.f,0.f,0.f,0.f}, ag = {0.f,0.f,0.f,0.f};
          #pragma unroll
          for (int half = 0; half < 2; ++half) {
            float4 wv[8];
            #pragma unroll
            for (int j = 0; j < 8; ++j) wv[j] = Wf[(half * 8 + j) * 32];
            #pragma unroll
            for (int j = 0; j < 8; ++j) {
              const int r = kc * 16 + half * 8 + j;
              float z = smW[r], g2 = smB2[r];
              fma4(az, z, wv[j]); fma4(ag, g2, wv[j]);
            }
          }
          smP4A[t] = az; smP4B[t] = ag; }  // idx = kc*32 + o4
        __syncthreads();
        if (t < 128) {
          const float* pa = (const float*)smP4A;
          const float* pb = (const float*)smP4B;
          float bo = P.bowB[l * 128 + t];
          float sz = 0.f, sg = 0.f;
          #pragma unroll
          for (int kc = 0; kc < 32; ++kc) { sz += pa[kc * 128 + t]; sg += pb[kc * 128 + t]; }
          rowNxt[t] = mishf(sz + bo);
          rowNxt[128 + t] = mishf(sg + bo);
        }
        __syncthreads();
      }
    }
  } else {
    // ================= Phase A: embed / pred0 / distances (dual) =================
    if (t < 256) {
      smX2[t] = P.X[(size_t)nA * 256 + t];
      smY2[t] = P.X[(size_t)nB * 256 + t];
      smNbr[t] = P.nbr[t];
    }
    if (t == 0) { smIA[256] = 0; smIB[256] = 0; }
    __syncthreads();
    { const int d = t & 63, ch = t >> 6;
      const float* W = P.embW + (ch * 16) * 64 + d;
      const float* xrA = smX2 + ch * 16;
      const float* xrB = smY2 + ch * 16;
      float aA = 0.f, aB = 0.f;
      #pragma unroll
      for (int f = 0; f < 16; ++f) {
        float w = W[f * 64];
        aA = fmaf(xrA[f], w, aA);
        aB = fmaf(xrB[f], w, aB);
      }
      smW[t] = aA; smB2[t] = aB; }
    { float pp = 0.f;
      if (t < 256) pp = smX2[t] * P.boutW[t];
      else if (t < 512) pp = smY2[t - 256] * P.boutW[t - 256];
      #pragma unroll
      for (int s = 32; s; s >>= 1) pp += __shfl_xor(pp, s);
      if (t < 512 && lane == 0) smH[wave] = pp; }   // waves 0..3 A, 4..7 B
    __syncthreads();
    if (t < 64) {
      float ndA = P.embB[t], ndB = P.embB[t];
      #pragma unroll
      for (int j = 0; j < 16; ++j) { ndA += smW[t + 64 * j]; ndB += smB2[t + 64 * j]; }
      smQA[t] = ndA; smKqA[t] = ndA;
      smQB[t] = ndB; smKqB[t] = ndB;
    }
    if (t == 0) {
      smPredA = smH[0] + smH[1] + smH[2] + smH[3] + P.boutB[0];
      smPredB = smH[4] + smH[5] + smH[6] + smH[7] + P.boutB[0];
    }
    if (t < 25) {
      ((float4*)rowBuf)[t]         = ((const float4*)(P.E + (size_t)nA * 100))[t];
      ((float4*)(rowBuf + 128))[t] = ((const float4*)(P.E + (size_t)nB * 100))[t];
    }
    __syncthreads();
    if (t < 512) {                      // distances: t<256 crystal A, else B
      const int m = t & 255, cr = t >> 8;
      const float4* em = (const float4*)(P.E + (size_t)m * 100);
      const float4* en = (const float4*)(cr ? (rowBuf + 128) : rowBuf);
      float sq = 0.f;
      #pragma unroll 5
      for (int jj = 0; jj < 25; ++jj) {
        float4 a = en[jj], c = em[jj];
        float dx = a.x - c.x, dy = a.y - c.y, dz = a.z - c.z, dw = a.w - c.w;
        sq += dx * dx + dy * dy + dz * dz + dw * dw;
      }
      float dd = (sq > 0.f) ? sqrtf(sq) : 0.f;
      // exp(-127*(d-c)^2) fp32-underflows to exactly 0 for d>=1.905.
      int mv;
      if (dd == 0.f) mv = -2;
      else if (dd < 1.905f) {
        int* sI = cr ? smIB : smIA;
        float* sD = cr ? smDB : smDA;
        int i = atomicAdd(&sI[256], 1);
        sI[i] = m; sD[i] = dd;
        mv = i;
      } else mv = -1;
      (cr ? smMapB : smMapA)[m] = mv;
    }
    __syncthreads();
    { int cntA = smIA[256]; if (cntA > 256) cntA = 256;   // rare RBF rows (none in data)
      for (int i = 0; i < cntA; ++i) if (t < 128) {
        float dd = smDA[i] - (float)t * (1.f / 127.f);
        P.rareRow[(size_t)(nA * 256 + i) * 128 + t] = expf(-127.f * dd * dd);
      }
      int cntB = smIB[256]; if (cntB > 256) cntB = 256;
      for (int i = 0; i < cntB; ++i) if (t < 128) {
        float dd = smDB[i] - (float)t * (1.f / 127.f);
        P.rareRow[(size_t)(nB * 256 + i) * 128 + t] = expf(-127.f * dd * dd);
      } }
    __syncthreads();

    // ============ Phase 1: dual q/k chains, float4 + batched loads ============
    for (int l = 0; l < 4; ++l) {
      // --- S0 partials: thread = (g, kc in 0..3, o4 in 0..127); 16 K each ---
      { const int g = t >> 9, u = t & 511;
        const int o4 = u & 127, kc = u >> 7;
        const float4* Wf = (const float4*)((g ? P.kpW : P.qpW) + (size_t)l * 32768)
                         + (size_t)(kc * 16) * 128 + o4;
        const float* xa = g ? smKqA : smQA;
        const float* xb = g ? smKqB : smQB;
        float4 aA = {0.f,0.f,0.f,0.f}, aB = {0.f,0.f,0.f,0.f};
        #pragma unroll
        for (int half = 0; half < 2; ++half) {
          float4 wv[8];
          #pragma unroll
          for (int j = 0; j < 8; ++j) wv[j] = Wf[(half * 8 + j) * 128];
          #pragma unroll
          for (int j = 0; j < 8; ++j) {
            const int r = kc * 16 + half * 8 + j;
            float x = xa[r], y = xb[r];
            fma4(aA, x, wv[j]); fma4(aB, y, wv[j]);
          }
        }
        smP4A[t] = aA; smP4B[t] = aB; }   // idx = g*512 + kc*128 + o4
      __syncthreads();
      // --- S0 reduce: output o per (g); write pq/pk + pkT ---
      { const int g = t >> 9, o = t & 511;
        const float* pa = (const float*)smP4A + g * 2048;
        const float* pb = (const float*)smP4B + g * 2048;
        float b0 = (g ? P.kpB : P.qpB)[l * 512 + o];
        float vA = b0 + pa[o] + pa[512 + o] + pa[1024 + o] + pa[1536 + o];
        float vB = b0 + pb[o] + pb[512 + o] + pb[1024 + o] + pb[1536 + o];
        if (g) {
          smKrA[o] = vA; smKrB[o] = vB;
          float2 st; st.x = vA; st.y = vB;
          *(float2*)(P.pkT + (size_t)l * 131072 + (size_t)o * 256 + nA) = st;
        } else { smPQA[l * 512 + o] = vA; smPQB[l * 512 + o] = vB; } }
      __syncthreads();
      if (l < 3) {
        // --- S2 partials: thread = (g, kc in 0..31, o4 in 0..15); 16 K each ---
        { const int g = t >> 9, u = t & 511;
          const int o4 = u & 15, kc = u >> 4;
          const float4* Wf = (const float4*)((g ? P.koW : P.qoW) + (size_t)l * 32768)
                           + (size_t)(kc * 16) * 16 + o4;
          const float* prA = g ? smKrA : (smPQA + l * 512);
          const float* prB = g ? smKrB : (smPQB + l * 512);
          float4 aA = {0.f,0.f,0.f,0.f}, aB = {0.f,0.f,0.f,0.f};
          #pragma unroll
          for (int half = 0; half < 2; ++half) {
            float4 wv[8];
            #pragma unroll
            for (int j = 0; j < 8; ++j) wv[j] = Wf[(half * 8 + j) * 16];
            #pragma unroll
            for (int j = 0; j < 8; ++j) {
              const int r = kc * 16 + half * 8 + j;
              const int pi = ((r & 3) << 7) | (r >> 2);
              float x = prA[pi], y = prB[pi];
              fma4(aA, x, wv[j]); fma4(aB, y, wv[j]);
            }
          }
          smP4A[t] = aA; smP4B[t] = aB; }  // idx = g*512 + kc*16 + o4
        __syncthreads();
        // --- S3: reduce + mish + LN (waves 0,1 / 8,9 handle A,B) ---
        { const int g = t >> 9, u = t & 511;
          if (u < 128) {
            const int cr = u >> 6, uu = u & 63;
            const float* src = (const float*)(cr ? smP4B : smP4A) + g * 2048;
            float acc = (g ? P.koB : P.qoB)[l * 64 + uu];
            #pragma unroll
            for (int kc = 0; kc < 32; ++kc) acc += src[kc * 64 + uu];
            float* x = g ? (cr ? smKqB : smKqA) : (cr ? smQB : smQA);
            float xv = x[uu] + mishf(acc);
            float mean = xv;
            #pragma unroll
            for (int s = 32; s; s >>= 1) mean += __shfl_xor(mean, s);
            mean *= (1.f / 64.f);
            float dv = xv - mean, var = dv * dv;
            #pragma unroll
            for (int s = 32; s; s >>= 1) var += __shfl_xor(var, s);
            var *= (1.f / 64.f);
            const float* G  = (g ? P.klnG : P.qlnG) + l * 64;
            const float* Bb = (g ? P.klnB : P.qlnB) + l * 64;
            x[uu] = dv * rsqrtf(var + 1e-5f) * G[uu] + Bb[uu];
          } }
        __syncthreads();
      }
      // rare-pair pipes for layer l (own-block; none in this data)
      { int cntA = smIA[256]; if (cntA > 256) cntA = 256;
        int cntB = smIB[256]; if (cntB > 256) cntB = 256;
        if (cntA + cntB > 0) {
          __syncthreads();
          for (int i = 0; i < cntA; ++i)
            rare_pipe(P.rareRow + (size_t)(nA * 256 + i) * 128,
                      P.rareDiff + ((size_t)nA * 256 + i) * 16 + l * 4,
                      P.bpW + (size_t)l * 65536, P.bpB + l * 512,
                      P.bowW + (size_t)l * 65536, P.bowB + l * 128, smW, smX2, t);
          for (int i = 0; i < cntB; ++i)
            rare_pipe(P.rareRow + (size_t)(nB * 256 + i) * 128,
                      P.rareDiff + ((size_t)nB * 256 + i) * 16 + l * 4,
                      P.bpW + (size_t)l * 65536, P.bpB + l * 512,
                      P.bowW + (size_t)l * 65536, P.bowB + l * 128, smW, smX2, t);
        } }
    }
  }

  grid.sync();   // the ONLY grid-wide sync: pkT + clsDiff now visible
  if (b >= 128) return;

  // ====== Phase 2: ALL (layer, head) attention, both crystals jammed ======
  if (t < 32) smDiff[t] = P.clsDiff[t];
  __syncthreads();
  {
    const int l = t >> 8, h = (t >> 6) & 3, mq = lane;   // wave = (l,h), lane = mq
    const float* qvA = smPQA + l * 512 + h * 128;
    const float* qvB = smPQB + l * 512 + h * 128;
    const float4* pt4 = (const float4*)P.pkT + (size_t)l * 32768 + (size_t)h * 128 * 64 + mq;
    float4 dA = {0.f, 0.f, 0.f, 0.f}, dB = {0.f, 0.f, 0.f, 0.f};
    for (int jb = 0; jb < 16; ++jb) {
      float4 vb[8];
      #pragma unroll
      for (int j = 0; j < 8; ++j) vb[j] = pt4[(size_t)(jb * 8 + j) * 64];
      #pragma unroll
      for (int j = 0; j < 8; ++j) {
        float a = qvA[jb * 8 + j], c = qvB[jb * 8 + j];
        fma4(dA, a, vb[j]); fma4(dB, c, vb[j]);
      }
    }
    auto epi = [&](const float4& dot, const int* sMap, int nn, float* oH) {
      float dArr[4] = {dot.x, dot.y, dot.z, dot.w};
      float lg[4], nb[4];
      int self = -1;
      #pragma unroll
      for (int i = 0; i < 4; ++i) {
        const int m = mq * 4 + i;
        const int cls = sMap[m];
        float bd;
        if (cls >= 0) bd = P.rareDiff[((size_t)nn * 256 + cls) * 16 + l * 4 + h];
        else bd = smDiff[(l * 2 + (cls == -1 ? 1 : 0)) * 4 + h];
        lg[i] = dArr[i] * 0.08838834764831845f + bd;   // 1/sqrt(128)
        nb[i] = smNbr[m];
        if (m == nn) { self = i; nb[i] = 0.f; }
      }
      float wm = fmaxf(fmaxf(lg[0], lg[1]), fmaxf(lg[2], lg[3]));
      #pragma unroll
      for (int s = 32; s; s >>= 1) wm = fmaxf(wm, __shfl_xor(wm, s));
      float sA = 0.f, sB = 0.f, sD = 0.f;
      #pragma unroll
      for (int i = 0; i < 4; ++i) {
        float e = expf(lg[i] - wm);
        sD += e;
        sA = fmaf(e, nb[i], sA);
        if (i == self) sB = e;
      }
      #pragma unroll
      for (int s = 32; s; s >>= 1) {
        sA += __shfl_xor(sA, s); sB += __shfl_xor(sB, s); sD += __shfl_xor(sD, s);
      }
      if (lane == 0) { oH[wave] = sA; oH[16 + wave] = sB; oH[32 + wave] = sD; }
    };
    epi(dA, smMapA, nA, smH);
    epi(dB, smMapB, nB, smH + 48);
  }
  __syncthreads();
  if (t == 0 || t == 64) {              // serial pred chains (A on wave0, B on wave1)
    const float* H = (t == 0) ? smH : smH + 48;
    float p = (t == 0) ? smPredA : smPredB;
    #pragma unroll
    for (int l = 0; l < 4; ++l) {
      float np = 0.f;
      #pragma unroll
      for (int h = 0; h < 4; ++h) {
        const int w = l * 4 + h;
        np += 0.25f * ((H[w] + H[16 + w] * p) / H[32 + w]);
      }
      p = np;
    }
    P.out[(t == 0) ? nA : nB] = p;
  }
}

// ---------------------------------------------------------------------------
extern "C" void kernel_launch(void* const* d_in, const int* in_sizes, int n_in,
                              void* d_out, int out_size, void* d_ws, size_t ws_size,
                              hipStream_t stream) {
  char* p = (char*)d_ws;
  auto carve = [&](size_t bytes) -> void* {
    void* r = (void*)p;
    p += (bytes + 255) & ~(size_t)255;
    return r;
  };

  Params P;
  P.X     = (const float*)d_in[0];
  P.E     = (const float*)d_in[1];
  P.nbr   = (const float*)d_in[2];
  P.embW  = (const float*)d_in[3];
  P.embB  = (const float*)d_in[4];
  P.boutW = (const float*)d_in[5];
  P.boutB = (const float*)d_in[6];
  P.qpW   = (const float*)d_in[7];
  P.qpB   = (const float*)d_in[8];
  P.kpW   = (const float*)d_in[9];
  P.kpB   = (const float*)d_in[10];
  P.qoW   = (const float*)d_in[11];
  P.qoB   = (const float*)d_in[12];
  P.koW   = (const float*)d_in[13];
  P.koB   = (const float*)d_in[14];
  P.bpW   = (const float*)d_in[15];
  P.bpB   = (const float*)d_in[16];
  P.bowW  = (const float*)d_in[17];
  P.bowB  = (const float*)d_in[18];
  P.qlnG  = (const float*)d_in[19];
  P.qlnB  = (const float*)d_in[20];
  P.klnG  = (const float*)d_in[21];
  P.klnB  = (const float*)d_in[22];
  P.out   = (float*)d_out;

  P.pkT      = (float*)carve((size_t)4 * 512 * 256 * 4);
  P.rareRow  = (float*)carve((size_t)65536 * 128 * 4);
  P.clsDiff  = (float*)carve((size_t)32 * 4);
  P.rareDiff = (float*)carve((size_t)256 * 256 * 16 * 4);

  void* args[] = { &P };
  hipLaunchCooperativeKernel((const void*)crakn, dim3(129), dim3(1024), args, 0, stream);
}

// Round 7
// 209.728 us; speedup vs baseline: 4.0296x; 3.9917x over previous
//
#include <hip/hip_runtime.h>
#include <hip/hip_cooperative_groups.h>

namespace cg = cooperative_groups;

struct Params {
  const float *X, *E, *nbr;
  const float *embW, *embB, *boutW, *boutB;
  const float *qpW, *qpB, *kpW, *kpB, *qoW, *qoB, *koW, *koB;
  const float *bpW, *bpB, *bowW, *bowB;
  const float *qlnG, *qlnB, *klnG, *klnB;
  float *out;
  float *pkT;      // [4][512][256] all-layer transposed keys
  float *rareRow;  // [65536][128] rare-pair bias rows (own-block use only)
  float *clsDiff;  // [4][2][4] class-bias norms from the dedicated bias block
  float *rareDiff; // [256][256][16] rare-pair diffs (own-block use only)
};

__device__ __forceinline__ float mishf(float x) {
  float sp = (x > 20.f) ? x : log1pf(expf(x));
  return x * tanhf(sp);
}

// Function, not macro — a macro param named `w` gets substituted into `acc.w`.
__device__ __forceinline__ void fma4(float4& acc, float s, const float4& v) {
  acc.x = fmaf(s, v.x, acc.x);
  acc.y = fmaf(s, v.y, acc.y);
  acc.z = fmaf(s, v.z, acc.z);
  acc.w = fmaf(s, v.w, acc.w);
}

// NAMED-register 8-deep load batch. An array `float4 wv[8]` goes to SCRATCH:
// SROA runs before unrolling, sees runtime indices, leaves the alloca ->
// every staged load becomes a scratch round-trip (rounds 5/6: 734MB FETCH /
// 392MB WRITE of pure spill traffic). Named SSA values cannot hit scratch.
// Macro params carry trailing underscores (hygiene vs member names).
#define LOAD8(Wp_, J0_, STRIDE_) \
  const float4 w0 = (Wp_)[(size_t)((J0_) + 0) * (STRIDE_)]; \
  const float4 w1 = (Wp_)[(size_t)((J0_) + 1) * (STRIDE_)]; \
  const float4 w2 = (Wp_)[(size_t)((J0_) + 2) * (STRIDE_)]; \
  const float4 w3 = (Wp_)[(size_t)((J0_) + 3) * (STRIDE_)]; \
  const float4 w4 = (Wp_)[(size_t)((J0_) + 4) * (STRIDE_)]; \
  const float4 w5 = (Wp_)[(size_t)((J0_) + 5) * (STRIDE_)]; \
  const float4 w6 = (Wp_)[(size_t)((J0_) + 6) * (STRIDE_)]; \
  const float4 w7 = (Wp_)[(size_t)((J0_) + 7) * (STRIDE_)];

// Full bias pipe for one rare-pair row, one layer (own-block; barriers inside).
// Cold correctness path (no rare pairs in this data) — scalar loads are fine.
__device__ void rare_pipe(float* row, float* drow,
                          const float* __restrict__ Wp, const float* __restrict__ Bp,
                          const float* __restrict__ Wo, const float* __restrict__ Bo,
                          float* smW, float* smS, int t) {
  const int lane = t & 63, wave = t >> 6;
  if (t < 128) smS[t] = row[t];
  __syncthreads();
  { const int o = t & 511, kh = t >> 9;
    const float* Wc = Wp + (kh * 64) * 512 + o;
    const float* rc = smS + kh * 64;
    float a = (kh == 0) ? Bp[o] : 0.f;
    #pragma unroll 8
    for (int c = 0; c < 64; ++c) a = fmaf(rc[c], Wc[c * 512], a);
    smW[t] = a; }
  __syncthreads();
  if (t < 512) smS[128 + t] = smW[t] + smW[512 + t];
  __syncthreads();
  if (wave < 4) {
    float e1 = smS[128 + wave * 128 + lane], e2 = smS[128 + wave * 128 + 64 + lane];
    float s = e1 * e1 + e2 * e2;
    #pragma unroll
    for (int sh = 32; sh; sh >>= 1) s += __shfl_xor(s, sh);
    if (lane == 0) drow[wave] = sqrtf(s);
  }
  { const int c = t & 127, ch = t >> 7;
    const float* Woc = Wo + (ch * 64) * 128 + c;
    const float* bc = smS + 128 + ch * 64;
    float a = 0.f;
    #pragma unroll 8
    for (int o2 = 0; o2 < 64; ++o2) a = fmaf(bc[o2], Woc[o2 * 128], a);
    smW[t] = a; }
  __syncthreads();
  if (t < 128) {
    float a = Bo[t];
    #pragma unroll
    for (int j = 0; j < 8; ++j) a += smW[t + 128 * j];
    row[t] = mishf(a);
  }
  __syncthreads();
}

// 129 blocks x 1024 threads; ONE grid.sync. (Cooperative cap: 1 block/CU -> <=256.)
// Blocks 0..127: DUAL-crystal chains (n = 2b, 2b+1) jammed on one weight stream.
// Block 128: the n-independent class-bias chain.
// Hot GEMVs: float4 weight loads along O + 8-deep NAMED-register load batches.
__global__ void __launch_bounds__(1024)
__attribute__((amdgpu_waves_per_eu(4, 4)))
crakn(Params P) {
  cg::grid_group grid = cg::this_grid();
  const int b = blockIdx.x, t = threadIdx.x;
  const int lane = t & 63, wave = t >> 6;
  const int nA = 2 * b, nB = 2 * b + 1;

  // persistent
  __shared__ __align__(16) float smPQA[2048];         // pq all layers, crystal A
  __shared__ __align__(16) float smPQB[2048];         // crystal B
  __shared__ __align__(16) float smKrA[512], smKrB[512];
  __shared__ __align__(16) float smQA[64], smQB[64], smKqA[64], smKqB[64];
  __shared__ __align__(16) float smNbr[256];
  __shared__ int   smMapA[256], smMapB[256];  // -2 zero-class, -1 gen-class, >=0 rare
  __shared__ float smDiff[32];                // [layer][class][head]
  __shared__ __align__(16) float rowBuf[512]; // bias block: class rows; crystal: E staging
  __shared__ float smPredA, smPredB;
  __shared__ int   smIA[257], smIB[257];
  __shared__ float smDA[256], smDB[256];
  // scratch
  __shared__ __align__(16) float4 smP4A[1024];        // partials (crystal A / class z)
  __shared__ __align__(16) float4 smP4B[1024];        // partials (crystal B / class g)
  __shared__ __align__(16) float smW[1024], smB2[1024], smX2[1024], smY2[1024];
  __shared__ float smH[128];

  if (b == 128) {
    // ================= Dedicated class-bias chain =================
    if (t < 128) {
      float c = (float)t * (1.f / 127.f);
      rowBuf[t] = expf(-127.f * c * c);  // zero class (d == 0)
      rowBuf[128 + t] = 0.f;             // gen class (underflowed)
    }
    __syncthreads();
    for (int l = 0; l < 4; ++l) {
      const float* rowCur = rowBuf + (l & 1) * 256;
      float* rowNxt = rowBuf + ((l + 1) & 1) * 256;
      // bias1 partials: thread = (kc in 0..7) x (o4 in 0..127); 16 K each
      { const int o4 = t & 127, kc = t >> 7;
        const float4* Wf = (const float4*)(P.bpW + (size_t)l * 65536) + (size_t)(kc * 16) * 128 + o4;
        float4 az = {0.f,0.f,0.f,0.f}, ag = {0.f,0.f,0.f,0.f};
        { LOAD8(Wf, 0, 128);
          const int r = kc * 16;
          fma4(az, rowCur[r+0], w0); fma4(ag, rowCur[128+r+0], w0);
          fma4(az, rowCur[r+1], w1); fma4(ag, rowCur[128+r+1], w1);
          fma4(az, rowCur[r+2], w2); fma4(ag, rowCur[128+r+2], w2);
          fma4(az, rowCur[r+3], w3); fma4(ag, rowCur[128+r+3], w3);
          fma4(az, rowCur[r+4], w4); fma4(ag, rowCur[128+r+4], w4);
          fma4(az, rowCur[r+5], w5); fma4(ag, rowCur[128+r+5], w5);
          fma4(az, rowCur[r+6], w6); fma4(ag, rowCur[128+r+6], w6);
          fma4(az, rowCur[r+7], w7); fma4(ag, rowCur[128+r+7], w7);
        }
        { LOAD8(Wf, 8, 128);
          const int r = kc * 16 + 8;
          fma4(az, rowCur[r+0], w0); fma4(ag, rowCur[128+r+0], w0);
          fma4(az, rowCur[r+1], w1); fma4(ag, rowCur[128+r+1], w1);
          fma4(az, rowCur[r+2], w2); fma4(ag, rowCur[128+r+2], w2);
          fma4(az, rowCur[r+3], w3); fma4(ag, rowCur[128+r+3], w3);
          fma4(az, rowCur[r+4], w4); fma4(ag, rowCur[128+r+4], w4);
          fma4(az, rowCur[r+5], w5); fma4(ag, rowCur[128+r+5], w5);
          fma4(az, rowCur[r+6], w6); fma4(ag, rowCur[128+r+6], w6);
          fma4(az, rowCur[r+7], w7); fma4(ag, rowCur[128+r+7], w7);
        }
        smP4A[t] = az; smP4B[t] = ag; }   // idx = kc*128 + o4
      __syncthreads();
      if (t < 512) {
        const float* pa = (const float*)smP4A;
        const float* pb = (const float*)smP4B;
        float bp = P.bpB[l * 512 + t];
        float z = bp, g2 = bp;
        #pragma unroll
        for (int kc = 0; kc < 8; ++kc) { z += pa[kc * 512 + t]; g2 += pb[kc * 512 + t]; }
        smW[t] = z; smB2[t] = g2;
      }
      __syncthreads();
      if (wave < 8) {                     // per-head norms -> global clsDiff
        const int cls = wave >> 2, h = wave & 3;
        const float* arr = cls ? smB2 : smW;
        float e1 = arr[h * 128 + lane], e2 = arr[h * 128 + 64 + lane];
        float s = e1 * e1 + e2 * e2;
        #pragma unroll
        for (int sh = 32; sh; sh >>= 1) s += __shfl_xor(s, sh);
        if (lane == 0) P.clsDiff[(l * 2 + cls) * 4 + h] = sqrtf(s);
      }
      if (l < 3) {
        // bias2 partials: thread = (kc in 0..31) x (o4 in 0..31); 16 K each
        { const int o4 = t & 31, kc = t >> 5;
          const float4* Wf = (const float4*)(P.bowW + (size_t)l * 65536) + (size_t)(kc * 16) * 32 + o4;
          float4 az = {0.f,0.f,0.f,0.f}, ag = {0.f,0.f,0.f,0.f};
          { LOAD8(Wf, 0, 32);
            const int r = kc * 16;
            fma4(az, smW[r+0], w0); fma4(ag, smB2[r+0], w0);
            fma4(az, smW[r+1], w1); fma4(ag, smB2[r+1], w1);
            fma4(az, smW[r+2], w2); fma4(ag, smB2[r+2], w2);
            fma4(az, smW[r+3], w3); fma4(ag, smB2[r+3], w3);
            fma4(az, smW[r+4], w4); fma4(ag, smB2[r+4], w4);
            fma4(az, smW[r+5], w5); fma4(ag, smB2[r+5], w5);
            fma4(az, smW[r+6], w6); fma4(ag, smB2[r+6], w6);
            fma4(az, smW[r+7], w7); fma4(ag, smB2[r+7], w7);
          }
          { LOAD8(Wf, 8, 32);
            const int r = kc * 16 + 8;
            fma4(az, smW[r+0], w0); fma4(ag, smB2[r+0], w0);
            fma4(az, smW[r+1], w1); fma4(ag, smB2[r+1], w1);
            fma4(az, smW[r+2], w2); fma4(ag, smB2[r+2], w2);
            fma4(az, smW[r+3], w3); fma4(ag, smB2[r+3], w3);
            fma4(az, smW[r+4], w4); fma4(ag, smB2[r+4], w4);
            fma4(az, smW[r+5], w5); fma4(ag, smB2[r+5], w5);
            fma4(az, smW[r+6], w6); fma4(ag, smB2[r+6], w6);
            fma4(az, smW[r+7], w7); fma4(ag, smB2[r+7], w7);
          }
          smP4A[t] = az; smP4B[t] = ag; }  // idx = kc*32 + o4
        __syncthreads();
        if (t < 128) {
          const float* pa = (const float*)smP4A;
          const float* pb = (const float*)smP4B;
          float bo = P.bowB[l * 128 + t];
          float sz = 0.f, sg = 0.f;
          #pragma unroll
          for (int kc = 0; kc < 32; ++kc) { sz += pa[kc * 128 + t]; sg += pb[kc * 128 + t]; }
          rowNxt[t] = mishf(sz + bo);
          rowNxt[128 + t] = mishf(sg + bo);
        }
        __syncthreads();
      }
    }
  } else {
    // ================= Phase A: embed / pred0 / distances (dual) =================
    if (t < 256) {
      smX2[t] = P.X[(size_t)nA * 256 + t];
      smY2[t] = P.X[(size_t)nB * 256 + t];
      smNbr[t] = P.nbr[t];
    }
    if (t == 0) { smIA[256] = 0; smIB[256] = 0; }
    __syncthreads();
    { const int d = t & 63, ch = t >> 6;
      const float* W = P.embW + (ch * 16) * 64 + d;
      const float* xrA = smX2 + ch * 16;
      const float* xrB = smY2 + ch * 16;
      float aA = 0.f, aB = 0.f;
      #pragma unroll
      for (int f = 0; f < 16; ++f) {
        float w = W[f * 64];
        aA = fmaf(xrA[f], w, aA);
        aB = fmaf(xrB[f], w, aB);
      }
      smW[t] = aA; smB2[t] = aB; }
    { float pp = 0.f;
      if (t < 256) pp = smX2[t] * P.boutW[t];
      else if (t < 512) pp = smY2[t - 256] * P.boutW[t - 256];
      #pragma unroll
      for (int s = 32; s; s >>= 1) pp += __shfl_xor(pp, s);
      if (t < 512 && lane == 0) smH[wave] = pp; }   // waves 0..3 A, 4..7 B
    __syncthreads();
    if (t < 64) {
      float ndA = P.embB[t], ndB = P.embB[t];
      #pragma unroll
      for (int j = 0; j < 16; ++j) { ndA += smW[t + 64 * j]; ndB += smB2[t + 64 * j]; }
      smQA[t] = ndA; smKqA[t] = ndA;
      smQB[t] = ndB; smKqB[t] = ndB;
    }
    if (t == 0) {
      smPredA = smH[0] + smH[1] + smH[2] + smH[3] + P.boutB[0];
      smPredB = smH[4] + smH[5] + smH[6] + smH[7] + P.boutB[0];
    }
    if (t < 25) {
      ((float4*)rowBuf)[t]         = ((const float4*)(P.E + (size_t)nA * 100))[t];
      ((float4*)(rowBuf + 128))[t] = ((const float4*)(P.E + (size_t)nB * 100))[t];
    }
    __syncthreads();
    if (t < 512) {                      // distances: t<256 crystal A, else B
      const int m = t & 255, cr = t >> 8;
      const float4* em = (const float4*)(P.E + (size_t)m * 100);
      const float4* en = (const float4*)(cr ? (rowBuf + 128) : rowBuf);
      float sq = 0.f;
      #pragma unroll 5
      for (int jj = 0; jj < 25; ++jj) {
        float4 a = en[jj], c = em[jj];
        float dx = a.x - c.x, dy = a.y - c.y, dz = a.z - c.z, dw = a.w - c.w;
        sq += dx * dx + dy * dy + dz * dz + dw * dw;
      }
      float dd = (sq > 0.f) ? sqrtf(sq) : 0.f;
      // exp(-127*(d-c)^2) fp32-underflows to exactly 0 for d>=1.905.
      int mv;
      if (dd == 0.f) mv = -2;
      else if (dd < 1.905f) {
        int* sI = cr ? smIB : smIA;
        float* sD = cr ? smDB : smDA;
        int i = atomicAdd(&sI[256], 1);
        sI[i] = m; sD[i] = dd;
        mv = i;
      } else mv = -1;
      (cr ? smMapB : smMapA)[m] = mv;
    }
    __syncthreads();
    { int cntA = smIA[256]; if (cntA > 256) cntA = 256;   // rare RBF rows (none in data)
      for (int i = 0; i < cntA; ++i) if (t < 128) {
        float dd = smDA[i] - (float)t * (1.f / 127.f);
        P.rareRow[(size_t)(nA * 256 + i) * 128 + t] = expf(-127.f * dd * dd);
      }
      int cntB = smIB[256]; if (cntB > 256) cntB = 256;
      for (int i = 0; i < cntB; ++i) if (t < 128) {
        float dd = smDB[i] - (float)t * (1.f / 127.f);
        P.rareRow[(size_t)(nB * 256 + i) * 128 + t] = expf(-127.f * dd * dd);
      } }
    __syncthreads();

    // ============ Phase 1: dual q/k chains, float4 + named-reg batches ============
    for (int l = 0; l < 4; ++l) {
      // --- S0 partials: thread = (g, kc in 0..3, o4 in 0..127); 16 K each ---
      { const int g = t >> 9, u = t & 511;
        const int o4 = u & 127, kc = u >> 7;
        const float4* Wf = (const float4*)((g ? P.kpW : P.qpW) + (size_t)l * 32768)
                         + (size_t)(kc * 16) * 128 + o4;
        const float* xa = g ? smKqA : smQA;
        const float* xb = g ? smKqB : smQB;
        float4 aA = {0.f,0.f,0.f,0.f}, aB = {0.f,0.f,0.f,0.f};
        { LOAD8(Wf, 0, 128);
          const int r = kc * 16;
          fma4(aA, xa[r+0], w0); fma4(aB, xb[r+0], w0);
          fma4(aA, xa[r+1], w1); fma4(aB, xb[r+1], w1);
          fma4(aA, xa[r+2], w2); fma4(aB, xb[r+2], w2);
          fma4(aA, xa[r+3], w3); fma4(aB, xb[r+3], w3);
          fma4(aA, xa[r+4], w4); fma4(aB, xb[r+4], w4);
          fma4(aA, xa[r+5], w5); fma4(aB, xb[r+5], w5);
          fma4(aA, xa[r+6], w6); fma4(aB, xb[r+6], w6);
          fma4(aA, xa[r+7], w7); fma4(aB, xb[r+7], w7);
        }
        { LOAD8(Wf, 8, 128);
          const int r = kc * 16 + 8;
          fma4(aA, xa[r+0], w0); fma4(aB, xb[r+0], w0);
          fma4(aA, xa[r+1], w1); fma4(aB, xb[r+1], w1);
          fma4(aA, xa[r+2], w2); fma4(aB, xb[r+2], w2);
          fma4(aA, xa[r+3], w3); fma4(aB, xb[r+3], w3);
          fma4(aA, xa[r+4], w4); fma4(aB, xb[r+4], w4);
          fma4(aA, xa[r+5], w5); fma4(aB, xb[r+5], w5);
          fma4(aA, xa[r+6], w6); fma4(aB, xb[r+6], w6);
          fma4(aA, xa[r+7], w7); fma4(aB, xb[r+7], w7);
        }
        smP4A[t] = aA; smP4B[t] = aB; }   // idx = g*512 + kc*128 + o4
      __syncthreads();
      // --- S0 reduce: output o per (g); write pq/pk + pkT ---
      { const int g = t >> 9, o = t & 511;
        const float* pa = (const float*)smP4A + g * 2048;
        const float* pb = (const float*)smP4B + g * 2048;
        float b0 = (g ? P.kpB : P.qpB)[l * 512 + o];
        float vA = b0 + pa[o] + pa[512 + o] + pa[1024 + o] + pa[1536 + o];
        float vB = b0 + pb[o] + pb[512 + o] + pb[1024 + o] + pb[1536 + o];
        if (g) {
          smKrA[o] = vA; smKrB[o] = vB;
          float2 st; st.x = vA; st.y = vB;
          *(float2*)(P.pkT + (size_t)l * 131072 + (size_t)o * 256 + nA) = st;
        } else { smPQA[l * 512 + o] = vA; smPQB[l * 512 + o] = vB; } }
      __syncthreads();
      if (l < 3) {
        // --- S2 partials: thread = (g, kc in 0..31, o4 in 0..15); 16 K each ---
        // pi(r) = ((r&3)<<7)|(r>>2); r = kc*16+off -> pi = ((off&3)<<7)|(kc*4+(off>>2))
        { const int g = t >> 9, u = t & 511;
          const int o4 = u & 15, kc = u >> 4;
          const float4* Wf = (const float4*)((g ? P.koW : P.qoW) + (size_t)l * 32768)
                           + (size_t)(kc * 16) * 16 + o4;
          const float* prA = g ? smKrA : (smPQA + l * 512);
          const float* prB = g ? smKrB : (smPQB + l * 512);
          const int pb0 = kc * 4;
          float4 aA = {0.f,0.f,0.f,0.f}, aB = {0.f,0.f,0.f,0.f};
          { LOAD8(Wf, 0, 16);
            fma4(aA, prA[pb0 + 0],       w0); fma4(aB, prB[pb0 + 0],       w0);
            fma4(aA, prA[128 + pb0],     w1); fma4(aB, prB[128 + pb0],     w1);
            fma4(aA, prA[256 + pb0],     w2); fma4(aB, prB[256 + pb0],     w2);
            fma4(aA, prA[384 + pb0],     w3); fma4(aB, prB[384 + pb0],     w3);
            fma4(aA, prA[pb0 + 1],       w4); fma4(aB, prB[pb0 + 1],       w4);
            fma4(aA, prA[128 + pb0 + 1], w5); fma4(aB, prB[128 + pb0 + 1], w5);
            fma4(aA, prA[256 + pb0 + 1], w6); fma4(aB, prB[256 + pb0 + 1], w6);
            fma4(aA, prA[384 + pb0 + 1], w7); fma4(aB, prB[384 + pb0 + 1], w7);
          }
          { LOAD8(Wf, 8, 16);
            fma4(aA, prA[pb0 + 2],       w0); fma4(aB, prB[pb0 + 2],       w0);
            fma4(aA, prA[128 + pb0 + 2], w1); fma4(aB, prB[128 + pb0 + 2], w1);
            fma4(aA, prA[256 + pb0 + 2], w2); fma4(aB, prB[256 + pb0 + 2], w2);
            fma4(aA, prA[384 + pb0 + 2], w3); fma4(aB, prB[384 + pb0 + 2], w3);
            fma4(aA, prA[pb0 + 3],       w4); fma4(aB, prB[pb0 + 3],       w4);
            fma4(aA, prA[128 + pb0 + 3], w5); fma4(aB, prB[128 + pb0 + 3], w5);
            fma4(aA, prA[256 + pb0 + 3], w6); fma4(aB, prB[256 + pb0 + 3], w6);
            fma4(aA, prA[384 + pb0 + 3], w7); fma4(aB, prB[384 + pb0 + 3], w7);
          }
          smP4A[t] = aA; smP4B[t] = aB; }  // idx = g*512 + kc*16 + o4
        __syncthreads();
        // --- S3: reduce + mish + LN (waves 0,1 / 8,9 handle A,B) ---
        { const int g = t >> 9, u = t & 511;
          if (u < 128) {
            const int cr = u >> 6, uu = u & 63;
            const float* src = (const float*)(cr ? smP4B : smP4A) + g * 2048;
            float acc = (g ? P.koB : P.qoB)[l * 64 + uu];
            #pragma unroll
            for (int kc = 0; kc < 32; ++kc) acc += src[kc * 64 + uu];
            float* x = g ? (cr ? smKqB : smKqA) : (cr ? smQB : smQA);
            float xv = x[uu] + mishf(acc);
            float mean = xv;
            #pragma unroll
            for (int s = 32; s; s >>= 1) mean += __shfl_xor(mean, s);
            mean *= (1.f / 64.f);
            float dv = xv - mean, var = dv * dv;
            #pragma unroll
            for (int s = 32; s; s >>= 1) var += __shfl_xor(var, s);
            var *= (1.f / 64.f);
            const float* G  = (g ? P.klnG : P.qlnG) + l * 64;
            const float* Bb = (g ? P.klnB : P.qlnB) + l * 64;
            x[uu] = dv * rsqrtf(var + 1e-5f) * G[uu] + Bb[uu];
          } }
        __syncthreads();
      }
      // rare-pair pipes for layer l (own-block; none in this data)
      { int cntA = smIA[256]; if (cntA > 256) cntA = 256;
        int cntB = smIB[256]; if (cntB > 256) cntB = 256;
        if (cntA + cntB > 0) {
          __syncthreads();
          for (int i = 0; i < cntA; ++i)
            rare_pipe(P.rareRow + (size_t)(nA * 256 + i) * 128,
                      P.rareDiff + ((size_t)nA * 256 + i) * 16 + l * 4,
                      P.bpW + (size_t)l * 65536, P.bpB + l * 512,
                      P.bowW + (size_t)l * 65536, P.bowB + l * 128, smW, smX2, t);
          for (int i = 0; i < cntB; ++i)
            rare_pipe(P.rareRow + (size_t)(nB * 256 + i) * 128,
                      P.rareDiff + ((size_t)nB * 256 + i) * 16 + l * 4,
                      P.bpW + (size_t)l * 65536, P.bpB + l * 512,
                      P.bowW + (size_t)l * 65536, P.bowB + l * 128, smW, smX2, t);
        } }
    }
  }

  grid.sync();   // the ONLY grid-wide sync: pkT + clsDiff now visible
  if (b >= 128) return;

  // ====== Phase 2: ALL (layer, head) attention, both crystals jammed ======
  if (t < 32) smDiff[t] = P.clsDiff[t];
  __syncthreads();
  {
    const int l = t >> 8, h = (t >> 6) & 3, mq = lane;   // wave = (l,h), lane = mq
    const float* qvA = smPQA + l * 512 + h * 128;
    const float* qvB = smPQB + l * 512 + h * 128;
    const float4* pt4 = (const float4*)P.pkT + (size_t)l * 32768 + (size_t)h * 128 * 64 + mq;
    float4 dA = {0.f, 0.f, 0.f, 0.f}, dB = {0.f, 0.f, 0.f, 0.f};
    for (int jb = 0; jb < 16; ++jb) {
      const int j0 = jb * 8;
      LOAD8(pt4, j0, 64);
      fma4(dA, qvA[j0+0], w0); fma4(dB, qvB[j0+0], w0);
      fma4(dA, qvA[j0+1], w1); fma4(dB, qvB[j0+1], w1);
      fma4(dA, qvA[j0+2], w2); fma4(dB, qvB[j0+2], w2);
      fma4(dA, qvA[j0+3], w3); fma4(dB, qvB[j0+3], w3);
      fma4(dA, qvA[j0+4], w4); fma4(dB, qvB[j0+4], w4);
      fma4(dA, qvA[j0+5], w5); fma4(dB, qvB[j0+5], w5);
      fma4(dA, qvA[j0+6], w6); fma4(dB, qvB[j0+6], w6);
      fma4(dA, qvA[j0+7], w7); fma4(dB, qvB[j0+7], w7);
    }
    auto epi = [&](const float4& dot, const int* sMap, int nn, float* oH) {
      float dArr[4] = {dot.x, dot.y, dot.z, dot.w};
      float lg[4], nb[4];
      int self = -1;
      #pragma unroll
      for (int i = 0; i < 4; ++i) {
        const int m = mq * 4 + i;
        const int cls = sMap[m];
        float bd;
        if (cls >= 0) bd = P.rareDiff[((size_t)nn * 256 + cls) * 16 + l * 4 + h];
        else bd = smDiff[(l * 2 + (cls == -1 ? 1 : 0)) * 4 + h];
        lg[i] = dArr[i] * 0.08838834764831845f + bd;   // 1/sqrt(128)
        nb[i] = smNbr[m];
        if (m == nn) { self = i; nb[i] = 0.f; }
      }
      float wm = fmaxf(fmaxf(lg[0], lg[1]), fmaxf(lg[2], lg[3]));
      #pragma unroll
      for (int s = 32; s; s >>= 1) wm = fmaxf(wm, __shfl_xor(wm, s));
      float sA = 0.f, sB = 0.f, sD = 0.f;
      #pragma unroll
      for (int i = 0; i < 4; ++i) {
        float e = expf(lg[i] - wm);
        sD += e;
        sA = fmaf(e, nb[i], sA);
        if (i == self) sB = e;
      }
      #pragma unroll
      for (int s = 32; s; s >>= 1) {
        sA += __shfl_xor(sA, s); sB += __shfl_xor(sB, s); sD += __shfl_xor(sD, s);
      }
      if (lane == 0) { oH[wave] = sA; oH[16 + wave] = sB; oH[32 + wave] = sD; }
    };
    epi(dA, smMapA, nA, smH);
    epi(dB, smMapB, nB, smH + 48);
  }
  __syncthreads();
  if (t == 0 || t == 64) {              // serial pred chains (A on wave0, B on wave1)
    const float* H = (t == 0) ? smH : smH + 48;
    float p = (t == 0) ? smPredA : smPredB;
    #pragma unroll
    for (int l = 0; l < 4; ++l) {
      float np = 0.f;
      #pragma unroll
      for (int h = 0; h < 4; ++h) {
        const int w = l * 4 + h;
        np += 0.25f * ((H[w] + H[16 + w] * p) / H[32 + w]);
      }
      p = np;
    }
    P.out[(t == 0) ? nA : nB] = p;
  }
}

// ---------------------------------------------------------------------------
extern "C" void kernel_launch(void* const* d_in, const int* in_sizes, int n_in,
                              void* d_out, int out_size, void* d_ws, size_t ws_size,
                              hipStream_t stream) {
  char* p = (char*)d_ws;
  auto carve = [&](size_t bytes) -> void* {
    void* r = (void*)p;
    p += (bytes + 255) & ~(size_t)255;
    return r;
  };

  Params P;
  P.X     = (const float*)d_in[0];
  P.E     = (const float*)d_in[1];
  P.nbr   = (const float*)d_in[2];
  P.embW  = (const float*)d_in[3];
  P.embB  = (const float*)d_in[4];
  P.boutW = (const float*)d_in[5];
  P.boutB = (const float*)d_in[6];
  P.qpW   = (const float*)d_in[7];
  P.qpB   = (const float*)d_in[8];
  P.kpW   = (const float*)d_in[9];
  P.kpB   = (const float*)d_in[10];
  P.qoW   = (const float*)d_in[11];
  P.qoB   = (const float*)d_in[12];
  P.koW   = (const float*)d_in[13];
  P.koB   = (const float*)d_in[14];
  P.bpW   = (const float*)d_in[15];
  P.bpB   = (const float*)d_in[16];
  P.bowW  = (const float*)d_in[17];
  P.bowB  = (const float*)d_in[18];
  P.qlnG  = (const float*)d_in[19];
  P.qlnB  = (const float*)d_in[20];
  P.klnG  = (const float*)d_in[21];
  P.klnB  = (const float*)d_in[22];
  P.out   = (float*)d_out;

  P.pkT      = (float*)carve((size_t)4 * 512 * 256 * 4);
  P.rareRow  = (float*)carve((size_t)65536 * 128 * 4);
  P.clsDiff  = (float*)carve((size_t)32 * 4);
  P.rareDiff = (float*)carve((size_t)256 * 256 * 16 * 4);

  void* args[] = { &P };
  hipLaunchCooperativeKernel((const void*)crakn, dim3(129), dim3(1024), args, 0, stream);
}

// Round 8
// 169.968 us; speedup vs baseline: 4.9723x; 1.2339x over previous
//
#include <hip/hip_runtime.h>

struct Params {
  const float *X, *E, *nbr;
  const float *embW, *embB, *boutW, *boutB;
  const float *qpW, *qpB, *kpW, *kpB, *qoW, *qoB, *koW, *koB;
  const float *bpW, *bpB, *bowW, *bowB;
  const float *qlnG, *qlnB, *klnG, *klnB;
  float *out;
  float *pkT;      // [4][512][256] all-layer transposed keys
  float *rareRow;  // [65536][128] rare-pair bias rows (own-block use only)
  float *clsDiff;  // [4][2][4] class-bias norms from the dedicated bias block
  float *rareDiff; // [256][256][16] rare-pair diffs (own-block use only)
  unsigned *bar;   // [64] grid-barrier state (memset to 0 every launch)
};

__device__ __forceinline__ float mishf(float x) {
  float sp = (x > 20.f) ? x : log1pf(expf(x));
  return x * tanhf(sp);
}

// Function, not macro — a macro param named `w` gets substituted into `acc.w`.
__device__ __forceinline__ void fma4(float4& acc, float s, const float4& v) {
  acc.x = fmaf(s, v.x, acc.x);
  acc.y = fmaf(s, v.y, acc.y);
  acc.z = fmaf(s, v.z, acc.z);
  acc.w = fmaf(s, v.w, acc.w);
}

// NAMED-register 8-deep load batch. An array `float4 wv[8]` goes to SCRATCH:
// SROA runs before unrolling, sees runtime indices, leaves the alloca ->
// every staged load becomes a scratch round-trip (rounds 5/6: 734MB FETCH /
// 392MB WRITE of pure spill traffic). Named SSA values cannot hit scratch.
#define LOAD8(Wp_, J0_, STRIDE_) \
  const float4 w0 = (Wp_)[(size_t)((J0_) + 0) * (STRIDE_)]; \
  const float4 w1 = (Wp_)[(size_t)((J0_) + 1) * (STRIDE_)]; \
  const float4 w2 = (Wp_)[(size_t)((J0_) + 2) * (STRIDE_)]; \
  const float4 w3 = (Wp_)[(size_t)((J0_) + 3) * (STRIDE_)]; \
  const float4 w4 = (Wp_)[(size_t)((J0_) + 4) * (STRIDE_)]; \
  const float4 w5 = (Wp_)[(size_t)((J0_) + 5) * (STRIDE_)]; \
  const float4 w6 = (Wp_)[(size_t)((J0_) + 6) * (STRIDE_)]; \
  const float4 w7 = (Wp_)[(size_t)((J0_) + 7) * (STRIDE_)];

// Hand-rolled single-use grid barrier (state memset to 0 before each launch,
// inside the same stream/graph). Semantically equivalent to cg::grid.sync()
// (which HIP implements as exactly this software barrier) — but lets us use a
// REGULAR kernel launch: hipLaunchCooperativeKernel takes a slow validation
// path under graph capture (~125us/iteration of fixed score overhead across
// rounds 0/3/7). Co-residency is guaranteed by construction: 129 blocks,
// 1 block/CU (LDS pad > 80KB), 256 CUs.
__device__ __forceinline__ void gridBarrier(unsigned* bar, unsigned nblocks) {
  __syncthreads();
  if (threadIdx.x == 0) {
    __threadfence();                         // publish this block's stores
    unsigned old = atomicAdd(bar, 1u);       // arrival count
    if (old == nblocks - 1u) {
      atomicExch(bar + 16, 1u);              // release flag (separate 64B)
    } else {
      while (atomicAdd(bar + 16, 0u) == 0u) {
        __builtin_amdgcn_s_sleep(2);
      }
    }
    __threadfence();                         // acquire before reading others'
  }
  __syncthreads();
}

// Full bias pipe for one rare-pair row, one layer (own-block; barriers inside).
// Cold correctness path (no rare pairs in this data) — scalar loads are fine.
__device__ void rare_pipe(float* row, float* drow,
                          const float* __restrict__ Wp, const float* __restrict__ Bp,
                          const float* __restrict__ Wo, const float* __restrict__ Bo,
                          float* smW, float* smS, int t) {
  const int lane = t & 63, wave = t >> 6;
  if (t < 128) smS[t] = row[t];
  __syncthreads();
  { const int o = t & 511, kh = t >> 9;
    const float* Wc = Wp + (kh * 64) * 512 + o;
    const float* rc = smS + kh * 64;
    float a = (kh == 0) ? Bp[o] : 0.f;
    #pragma unroll 8
    for (int c = 0; c < 64; ++c) a = fmaf(rc[c], Wc[c * 512], a);
    smW[t] = a; }
  __syncthreads();
  if (t < 512) smS[128 + t] = smW[t] + smW[512 + t];
  __syncthreads();
  if (wave < 4) {
    float e1 = smS[128 + wave * 128 + lane], e2 = smS[128 + wave * 128 + 64 + lane];
    float s = e1 * e1 + e2 * e2;
    #pragma unroll
    for (int sh = 32; sh; sh >>= 1) s += __shfl_xor(s, sh);
    if (lane == 0) drow[wave] = sqrtf(s);
  }
  { const int c = t & 127, ch = t >> 7;
    const float* Woc = Wo + (ch * 64) * 128 + c;
    const float* bc = smS + 128 + ch * 64;
    float a = 0.f;
    #pragma unroll 8
    for (int o2 = 0; o2 < 64; ++o2) a = fmaf(bc[o2], Woc[o2 * 128], a);
    smW[t] = a; }
  __syncthreads();
  if (t < 128) {
    float a = Bo[t];
    #pragma unroll
    for (int j = 0; j < 8; ++j) a += smW[t + 128 * j];
    row[t] = mishf(a);
  }
  __syncthreads();
}

// 129 blocks x 1024 threads; ONE grid-wide barrier.
// Blocks 0..127: DUAL-crystal chains (n = 2b, 2b+1) jammed on one weight stream.
// Block 128: the n-independent class-bias chain.
// Hot GEMVs: float4 weight loads along O + 8-deep NAMED-register load batches.
__global__ void __launch_bounds__(1024)
__attribute__((amdgpu_waves_per_eu(4, 4)))
crakn(Params P) {
  const int b = blockIdx.x, t = threadIdx.x;
  const int lane = t & 63, wave = t >> 6;
  const int nA = 2 * b, nB = 2 * b + 1;

  // persistent
  __shared__ __align__(16) float smPQA[2048];         // pq all layers, crystal A
  __shared__ __align__(16) float smPQB[2048];         // crystal B
  __shared__ __align__(16) float smKrA[512], smKrB[512];
  __shared__ __align__(16) float smQA[64], smQB[64], smKqA[64], smKqB[64];
  __shared__ __align__(16) float smNbr[256];
  __shared__ int   smMapA[256], smMapB[256];  // -2 zero-class, -1 gen-class, >=0 rare
  __shared__ float smDiff[32];                // [layer][class][head]
  __shared__ __align__(16) float rowBuf[512]; // bias block: class rows; crystal: E staging
  __shared__ float smPredA, smPredB;
  __shared__ int   smIA[257], smIB[257];
  __shared__ float smDA[256], smDB[256];
  // scratch
  __shared__ __align__(16) float4 smP4A[1024];        // partials (crystal A / class z)
  __shared__ __align__(16) float4 smP4B[1024];        // partials (crystal B / class g)
  __shared__ __align__(16) float smW[1024], smB2[1024], smX2[1024], smY2[1024];
  __shared__ float smH[128];
  // LDS pad: push block LDS above 80KB so only ONE block fits per CU -> the
  // scheduler must spread all 129 blocks across distinct CUs (co-residency
  // for the hand-rolled barrier is then guaranteed by construction).
  __shared__ float smPad[512];
  if (((size_t)P.out) == 1) smPad[t & 511] = 1.f;  // opaque guard: keep allocation

  if (b == 128) {
    // ================= Dedicated class-bias chain =================
    if (t < 128) {
      float c = (float)t * (1.f / 127.f);
      rowBuf[t] = expf(-127.f * c * c);  // zero class (d == 0)
      rowBuf[128 + t] = 0.f;             // gen class (underflowed)
    }
    __syncthreads();
    for (int l = 0; l < 4; ++l) {
      const float* rowCur = rowBuf + (l & 1) * 256;
      float* rowNxt = rowBuf + ((l + 1) & 1) * 256;
      // bias1 partials: thread = (kc in 0..7) x (o4 in 0..127); 16 K each
      { const int o4 = t & 127, kc = t >> 7;
        const float4* Wf = (const float4*)(P.bpW + (size_t)l * 65536) + (size_t)(kc * 16) * 128 + o4;
        float4 az = {0.f,0.f,0.f,0.f}, ag = {0.f,0.f,0.f,0.f};
        { LOAD8(Wf, 0, 128);
          const int r = kc * 16;
          fma4(az, rowCur[r+0], w0); fma4(ag, rowCur[128+r+0], w0);
          fma4(az, rowCur[r+1], w1); fma4(ag, rowCur[128+r+1], w1);
          fma4(az, rowCur[r+2], w2); fma4(ag, rowCur[128+r+2], w2);
          fma4(az, rowCur[r+3], w3); fma4(ag, rowCur[128+r+3], w3);
          fma4(az, rowCur[r+4], w4); fma4(ag, rowCur[128+r+4], w4);
          fma4(az, rowCur[r+5], w5); fma4(ag, rowCur[128+r+5], w5);
          fma4(az, rowCur[r+6], w6); fma4(ag, rowCur[128+r+6], w6);
          fma4(az, rowCur[r+7], w7); fma4(ag, rowCur[128+r+7], w7);
        }
        { LOAD8(Wf, 8, 128);
          const int r = kc * 16 + 8;
          fma4(az, rowCur[r+0], w0); fma4(ag, rowCur[128+r+0], w0);
          fma4(az, rowCur[r+1], w1); fma4(ag, rowCur[128+r+1], w1);
          fma4(az, rowCur[r+2], w2); fma4(ag, rowCur[128+r+2], w2);
          fma4(az, rowCur[r+3], w3); fma4(ag, rowCur[128+r+3], w3);
          fma4(az, rowCur[r+4], w4); fma4(ag, rowCur[128+r+4], w4);
          fma4(az, rowCur[r+5], w5); fma4(ag, rowCur[128+r+5], w5);
          fma4(az, rowCur[r+6], w6); fma4(ag, rowCur[128+r+6], w6);
          fma4(az, rowCur[r+7], w7); fma4(ag, rowCur[128+r+7], w7);
        }
        smP4A[t] = az; smP4B[t] = ag; }   // idx = kc*128 + o4
      __syncthreads();
      if (t < 512) {
        const float* pa = (const float*)smP4A;
        const float* pb = (const float*)smP4B;
        float bp = P.bpB[l * 512 + t];
        float z = bp, g2 = bp;
        #pragma unroll
        for (int kc = 0; kc < 8; ++kc) { z += pa[kc * 512 + t]; g2 += pb[kc * 512 + t]; }
        smW[t] = z; smB2[t] = g2;
      }
      __syncthreads();
      if (wave < 8) {                     // per-head norms -> global clsDiff
        const int cls = wave >> 2, h = wave & 3;
        const float* arr = cls ? smB2 : smW;
        float e1 = arr[h * 128 + lane], e2 = arr[h * 128 + 64 + lane];
        float s = e1 * e1 + e2 * e2;
        #pragma unroll
        for (int sh = 32; sh; sh >>= 1) s += __shfl_xor(s, sh);
        if (lane == 0) P.clsDiff[(l * 2 + cls) * 4 + h] = sqrtf(s);
      }
      if (l < 3) {
        // bias2 partials: thread = (kc in 0..31) x (o4 in 0..31); 16 K each
        { const int o4 = t & 31, kc = t >> 5;
          const float4* Wf = (const float4*)(P.bowW + (size_t)l * 65536) + (size_t)(kc * 16) * 32 + o4;
          float4 az = {0.f,0.f,0.f,0.f}, ag = {0.f,0.f,0.f,0.f};
          { LOAD8(Wf, 0, 32);
            const int r = kc * 16;
            fma4(az, smW[r+0], w0); fma4(ag, smB2[r+0], w0);
            fma4(az, smW[r+1], w1); fma4(ag, smB2[r+1], w1);
            fma4(az, smW[r+2], w2); fma4(ag, smB2[r+2], w2);
            fma4(az, smW[r+3], w3); fma4(ag, smB2[r+3], w3);
            fma4(az, smW[r+4], w4); fma4(ag, smB2[r+4], w4);
            fma4(az, smW[r+5], w5); fma4(ag, smB2[r+5], w5);
            fma4(az, smW[r+6], w6); fma4(ag, smB2[r+6], w6);
            fma4(az, smW[r+7], w7); fma4(ag, smB2[r+7], w7);
          }
          { LOAD8(Wf, 8, 32);
            const int r = kc * 16 + 8;
            fma4(az, smW[r+0], w0); fma4(ag, smB2[r+0], w0);
            fma4(az, smW[r+1], w1); fma4(ag, smB2[r+1], w1);
            fma4(az, smW[r+2], w2); fma4(ag, smB2[r+2], w2);
            fma4(az, smW[r+3], w3); fma4(ag, smB2[r+3], w3);
            fma4(az, smW[r+4], w4); fma4(ag, smB2[r+4], w4);
            fma4(az, smW[r+5], w5); fma4(ag, smB2[r+5], w5);
            fma4(az, smW[r+6], w6); fma4(ag, smB2[r+6], w6);
            fma4(az, smW[r+7], w7); fma4(ag, smB2[r+7], w7);
          }
          smP4A[t] = az; smP4B[t] = ag; }  // idx = kc*32 + o4
        __syncthreads();
        if (t < 128) {
          const float* pa = (const float*)smP4A;
          const float* pb = (const float*)smP4B;
          float bo = P.bowB[l * 128 + t];
          float sz = 0.f, sg = 0.f;
          #pragma unroll
          for (int kc = 0; kc < 32; ++kc) { sz += pa[kc * 128 + t]; sg += pb[kc * 128 + t]; }
          rowNxt[t] = mishf(sz + bo);
          rowNxt[128 + t] = mishf(sg + bo);
        }
        __syncthreads();
      }
    }
  } else {
    // ================= Phase A: embed / pred0 / distances (dual) =================
    if (t < 256) {
      smX2[t] = P.X[(size_t)nA * 256 + t];
      smY2[t] = P.X[(size_t)nB * 256 + t];
      smNbr[t] = P.nbr[t];
    }
    if (t == 0) { smIA[256] = 0; smIB[256] = 0; }
    __syncthreads();
    { const int d = t & 63, ch = t >> 6;
      const float* W = P.embW + (ch * 16) * 64 + d;
      const float* xrA = smX2 + ch * 16;
      const float* xrB = smY2 + ch * 16;
      float aA = 0.f, aB = 0.f;
      #pragma unroll
      for (int f = 0; f < 16; ++f) {
        float w = W[f * 64];
        aA = fmaf(xrA[f], w, aA);
        aB = fmaf(xrB[f], w, aB);
      }
      smW[t] = aA; smB2[t] = aB; }
    { float pp = 0.f;
      if (t < 256) pp = smX2[t] * P.boutW[t];
      else if (t < 512) pp = smY2[t - 256] * P.boutW[t - 256];
      #pragma unroll
      for (int s = 32; s; s >>= 1) pp += __shfl_xor(pp, s);
      if (t < 512 && lane == 0) smH[wave] = pp; }   // waves 0..3 A, 4..7 B
    __syncthreads();
    if (t < 64) {
      float ndA = P.embB[t], ndB = P.embB[t];
      #pragma unroll
      for (int j = 0; j < 16; ++j) { ndA += smW[t + 64 * j]; ndB += smB2[t + 64 * j]; }
      smQA[t] = ndA; smKqA[t] = ndA;
      smQB[t] = ndB; smKqB[t] = ndB;
    }
    if (t == 0) {
      smPredA = smH[0] + smH[1] + smH[2] + smH[3] + P.boutB[0];
      smPredB = smH[4] + smH[5] + smH[6] + smH[7] + P.boutB[0];
    }
    if (t < 25) {
      ((float4*)rowBuf)[t]         = ((const float4*)(P.E + (size_t)nA * 100))[t];
      ((float4*)(rowBuf + 128))[t] = ((const float4*)(P.E + (size_t)nB * 100))[t];
    }
    __syncthreads();
    if (t < 512) {                      // distances: t<256 crystal A, else B
      const int m = t & 255, cr = t >> 8;
      const float4* em = (const float4*)(P.E + (size_t)m * 100);
      const float4* en = (const float4*)(cr ? (rowBuf + 128) : rowBuf);
      float sq = 0.f;
      #pragma unroll 5
      for (int jj = 0; jj < 25; ++jj) {
        float4 a = en[jj], c = em[jj];
        float dx = a.x - c.x, dy = a.y - c.y, dz = a.z - c.z, dw = a.w - c.w;
        sq += dx * dx + dy * dy + dz * dz + dw * dw;
      }
      float dd = (sq > 0.f) ? sqrtf(sq) : 0.f;
      // exp(-127*(d-c)^2) fp32-underflows to exactly 0 for d>=1.905.
      int mv;
      if (dd == 0.f) mv = -2;
      else if (dd < 1.905f) {
        int* sI = cr ? smIB : smIA;
        float* sD = cr ? smDB : smDA;
        int i = atomicAdd(&sI[256], 1);
        sI[i] = m; sD[i] = dd;
        mv = i;
      } else mv = -1;
      (cr ? smMapB : smMapA)[m] = mv;
    }
    __syncthreads();
    { int cntA = smIA[256]; if (cntA > 256) cntA = 256;   // rare RBF rows (none in data)
      for (int i = 0; i < cntA; ++i) if (t < 128) {
        float dd = smDA[i] - (float)t * (1.f / 127.f);
        P.rareRow[(size_t)(nA * 256 + i) * 128 + t] = expf(-127.f * dd * dd);
      }
      int cntB = smIB[256]; if (cntB > 256) cntB = 256;
      for (int i = 0; i < cntB; ++i) if (t < 128) {
        float dd = smDB[i] - (float)t * (1.f / 127.f);
        P.rareRow[(size_t)(nB * 256 + i) * 128 + t] = expf(-127.f * dd * dd);
      } }
    __syncthreads();

    // ============ Phase 1: dual q/k chains, float4 + named-reg batches ============
    for (int l = 0; l < 4; ++l) {
      // --- S0 partials: thread = (g, kc in 0..3, o4 in 0..127); 16 K each ---
      { const int g = t >> 9, u = t & 511;
        const int o4 = u & 127, kc = u >> 7;
        const float4* Wf = (const float4*)((g ? P.kpW : P.qpW) + (size_t)l * 32768)
                         + (size_t)(kc * 16) * 128 + o4;
        const float* xa = g ? smKqA : smQA;
        const float* xb = g ? smKqB : smQB;
        float4 aA = {0.f,0.f,0.f,0.f}, aB = {0.f,0.f,0.f,0.f};
        { LOAD8(Wf, 0, 128);
          const int r = kc * 16;
          fma4(aA, xa[r+0], w0); fma4(aB, xb[r+0], w0);
          fma4(aA, xa[r+1], w1); fma4(aB, xb[r+1], w1);
          fma4(aA, xa[r+2], w2); fma4(aB, xb[r+2], w2);
          fma4(aA, xa[r+3], w3); fma4(aB, xb[r+3], w3);
          fma4(aA, xa[r+4], w4); fma4(aB, xb[r+4], w4);
          fma4(aA, xa[r+5], w5); fma4(aB, xb[r+5], w5);
          fma4(aA, xa[r+6], w6); fma4(aB, xb[r+6], w6);
          fma4(aA, xa[r+7], w7); fma4(aB, xb[r+7], w7);
        }
        { LOAD8(Wf, 8, 128);
          const int r = kc * 16 + 8;
          fma4(aA, xa[r+0], w0); fma4(aB, xb[r+0], w0);
          fma4(aA, xa[r+1], w1); fma4(aB, xb[r+1], w1);
          fma4(aA, xa[r+2], w2); fma4(aB, xb[r+2], w2);
          fma4(aA, xa[r+3], w3); fma4(aB, xb[r+3], w3);
          fma4(aA, xa[r+4], w4); fma4(aB, xb[r+4], w4);
          fma4(aA, xa[r+5], w5); fma4(aB, xb[r+5], w5);
          fma4(aA, xa[r+6], w6); fma4(aB, xb[r+6], w6);
          fma4(aA, xa[r+7], w7); fma4(aB, xb[r+7], w7);
        }
        smP4A[t] = aA; smP4B[t] = aB; }   // idx = g*512 + kc*128 + o4
      __syncthreads();
      // --- S0 reduce: output o per (g); write pq/pk + pkT ---
      { const int g = t >> 9, o = t & 511;
        const float* pa = (const float*)smP4A + g * 2048;
        const float* pb = (const float*)smP4B + g * 2048;
        float b0 = (g ? P.kpB : P.qpB)[l * 512 + o];
        float vA = b0 + pa[o] + pa[512 + o] + pa[1024 + o] + pa[1536 + o];
        float vB = b0 + pb[o] + pb[512 + o] + pb[1024 + o] + pb[1536 + o];
        if (g) {
          smKrA[o] = vA; smKrB[o] = vB;
          float2 st; st.x = vA; st.y = vB;
          *(float2*)(P.pkT + (size_t)l * 131072 + (size_t)o * 256 + nA) = st;
        } else { smPQA[l * 512 + o] = vA; smPQB[l * 512 + o] = vB; } }
      __syncthreads();
      if (l < 3) {
        // --- S2 partials: thread = (g, kc in 0..31, o4 in 0..15); 16 K each ---
        // pi(r) = ((r&3)<<7)|(r>>2); r = kc*16+off -> pi = ((off&3)<<7)|(kc*4+(off>>2))
        { const int g = t >> 9, u = t & 511;
          const int o4 = u & 15, kc = u >> 4;
          const float4* Wf = (const float4*)((g ? P.koW : P.qoW) + (size_t)l * 32768)
                           + (size_t)(kc * 16) * 16 + o4;
          const float* prA = g ? smKrA : (smPQA + l * 512);
          const float* prB = g ? smKrB : (smPQB + l * 512);
          const int pb0 = kc * 4;
          float4 aA = {0.f,0.f,0.f,0.f}, aB = {0.f,0.f,0.f,0.f};
          { LOAD8(Wf, 0, 16);
            fma4(aA, prA[pb0 + 0],       w0); fma4(aB, prB[pb0 + 0],       w0);
            fma4(aA, prA[128 + pb0],     w1); fma4(aB, prB[128 + pb0],     w1);
            fma4(aA, prA[256 + pb0],     w2); fma4(aB, prB[256 + pb0],     w2);
            fma4(aA, prA[384 + pb0],     w3); fma4(aB, prB[384 + pb0],     w3);
            fma4(aA, prA[pb0 + 1],       w4); fma4(aB, prB[pb0 + 1],       w4);
            fma4(aA, prA[128 + pb0 + 1], w5); fma4(aB, prB[128 + pb0 + 1], w5);
            fma4(aA, prA[256 + pb0 + 1], w6); fma4(aB, prB[256 + pb0 + 1], w6);
            fma4(aA, prA[384 + pb0 + 1], w7); fma4(aB, prB[384 + pb0 + 1], w7);
          }
          { LOAD8(Wf, 8, 16);
            fma4(aA, prA[pb0 + 2],       w0); fma4(aB, prB[pb0 + 2],       w0);
            fma4(aA, prA[128 + pb0 + 2], w1); fma4(aB, prB[128 + pb0 + 2], w1);
            fma4(aA, prA[256 + pb0 + 2], w2); fma4(aB, prB[256 + pb0 + 2], w2);
            fma4(aA, prA[384 + pb0 + 2], w3); fma4(aB, prB[384 + pb0 + 2], w3);
            fma4(aA, prA[pb0 + 3],       w4); fma4(aB, prB[pb0 + 3],       w4);
            fma4(aA, prA[128 + pb0 + 3], w5); fma4(aB, prB[128 + pb0 + 3], w5);
            fma4(aA, prA[256 + pb0 + 3], w6); fma4(aB, prB[256 + pb0 + 3], w6);
            fma4(aA, prA[384 + pb0 + 3], w7); fma4(aB, prB[384 + pb0 + 3], w7);
          }
          smP4A[t] = aA; smP4B[t] = aB; }  // idx = g*512 + kc*16 + o4
        __syncthreads();
        // --- S3: reduce + mish + LN (waves 0,1 / 8,9 handle A,B) ---
        { const int g = t >> 9, u = t & 511;
          if (u < 128) {
            const int cr = u >> 6, uu = u & 63;
            const float* src = (const float*)(cr ? smP4B : smP4A) + g * 2048;
            float acc = (g ? P.koB : P.qoB)[l * 64 + uu];
            #pragma unroll
            for (int kc = 0; kc < 32; ++kc) acc += src[kc * 64 + uu];
            float* x = g ? (cr ? smKqB : smKqA) : (cr ? smQB : smQA);
            float xv = x[uu] + mishf(acc);
            float mean = xv;
            #pragma unroll
            for (int s = 32; s; s >>= 1) mean += __shfl_xor(mean, s);
            mean *= (1.f / 64.f);
            float dv = xv - mean, var = dv * dv;
            #pragma unroll
            for (int s = 32; s; s >>= 1) var += __shfl_xor(var, s);
            var *= (1.f / 64.f);
            const float* G  = (g ? P.klnG : P.qlnG) + l * 64;
            const float* Bb = (g ? P.klnB : P.qlnB) + l * 64;
            x[uu] = dv * rsqrtf(var + 1e-5f) * G[uu] + Bb[uu];
          } }
        __syncthreads();
      }
      // rare-pair pipes for layer l (own-block; none in this data)
      { int cntA = smIA[256]; if (cntA > 256) cntA = 256;
        int cntB = smIB[256]; if (cntB > 256) cntB = 256;
        if (cntA + cntB > 0) {
          __syncthreads();
          for (int i = 0; i < cntA; ++i)
            rare_pipe(P.rareRow + (size_t)(nA * 256 + i) * 128,
                      P.rareDiff + ((size_t)nA * 256 + i) * 16 + l * 4,
                      P.bpW + (size_t)l * 65536, P.bpB + l * 512,
                      P.bowW + (size_t)l * 65536, P.bowB + l * 128, smW, smX2, t);
          for (int i = 0; i < cntB; ++i)
            rare_pipe(P.rareRow + (size_t)(nB * 256 + i) * 128,
                      P.rareDiff + ((size_t)nB * 256 + i) * 16 + l * 4,
                      P.bpW + (size_t)l * 65536, P.bpB + l * 512,
                      P.bowW + (size_t)l * 65536, P.bowB + l * 128, smW, smX2, t);
        } }
    }
  }

  gridBarrier(P.bar, 129);   // the ONLY grid-wide sync: pkT + clsDiff now visible
  if (b >= 128) return;

  // ====== Phase 2: ALL (layer, head) attention, both crystals jammed ======
  if (t < 32) smDiff[t] = P.clsDiff[t];
  __syncthreads();
  {
    const int l = t >> 8, h = (t >> 6) & 3, mq = lane;   // wave = (l,h), lane = mq
    const float* qvA = smPQA + l * 512 + h * 128;
    const float* qvB = smPQB + l * 512 + h * 128;
    const float4* pt4 = (const float4*)P.pkT + (size_t)l * 32768 + (size_t)h * 128 * 64 + mq;
    float4 dA = {0.f, 0.f, 0.f, 0.f}, dB = {0.f, 0.f, 0.f, 0.f};
    for (int jb = 0; jb < 16; ++jb) {
      const int j0 = jb * 8;
      LOAD8(pt4, j0, 64);
      fma4(dA, qvA[j0+0], w0); fma4(dB, qvB[j0+0], w0);
      fma4(dA, qvA[j0+1], w1); fma4(dB, qvB[j0+1], w1);
      fma4(dA, qvA[j0+2], w2); fma4(dB, qvB[j0+2], w2);
      fma4(dA, qvA[j0+3], w3); fma4(dB, qvB[j0+3], w3);
      fma4(dA, qvA[j0+4], w4); fma4(dB, qvB[j0+4], w4);
      fma4(dA, qvA[j0+5], w5); fma4(dB, qvB[j0+5], w5);
      fma4(dA, qvA[j0+6], w6); fma4(dB, qvB[j0+6], w6);
      fma4(dA, qvA[j0+7], w7); fma4(dB, qvB[j0+7], w7);
    }
    auto epi = [&](const float4& dot, const int* sMap, int nn, float* oH) {
      float dArr[4] = {dot.x, dot.y, dot.z, dot.w};
      float lg[4], nb[4];
      int self = -1;
      #pragma unroll
      for (int i = 0; i < 4; ++i) {
        const int m = mq * 4 + i;
        const int cls = sMap[m];
        float bd;
        if (cls >= 0) bd = P.rareDiff[((size_t)nn * 256 + cls) * 16 + l * 4 + h];
        else bd = smDiff[(l * 2 + (cls == -1 ? 1 : 0)) * 4 + h];
        lg[i] = dArr[i] * 0.08838834764831845f + bd;   // 1/sqrt(128)
        nb[i] = smNbr[m];
        if (m == nn) { self = i; nb[i] = 0.f; }
      }
      float wm = fmaxf(fmaxf(lg[0], lg[1]), fmaxf(lg[2], lg[3]));
      #pragma unroll
      for (int s = 32; s; s >>= 1) wm = fmaxf(wm, __shfl_xor(wm, s));
      float sA = 0.f, sB = 0.f, sD = 0.f;
      #pragma unroll
      for (int i = 0; i < 4; ++i) {
        float e = expf(lg[i] - wm);
        sD += e;
        sA = fmaf(e, nb[i], sA);
        if (i == self) sB = e;
      }
      #pragma unroll
      for (int s = 32; s; s >>= 1) {
        sA += __shfl_xor(sA, s); sB += __shfl_xor(sB, s); sD += __shfl_xor(sD, s);
      }
      if (lane == 0) { oH[wave] = sA; oH[16 + wave] = sB; oH[32 + wave] = sD; }
    };
    epi(dA, smMapA, nA, smH);
    epi(dB, smMapB, nB, smH + 48);
  }
  __syncthreads();
  if (t == 0 || t == 64) {              // serial pred chains (A on wave0, B on wave1)
    const float* H = (t == 0) ? smH : smH + 48;
    float p = (t == 0) ? smPredA : smPredB;
    #pragma unroll
    for (int l = 0; l < 4; ++l) {
      float np = 0.f;
      #pragma unroll
      for (int h = 0; h < 4; ++h) {
        const int w = l * 4 + h;
        np += 0.25f * ((H[w] + H[16 + w] * p) / H[32 + w]);
      }
      p = np;
    }
    P.out[(t == 0) ? nA : nB] = p;
  }
}

// ---------------------------------------------------------------------------
extern "C" void kernel_launch(void* const* d_in, const int* in_sizes, int n_in,
                              void* d_out, int out_size, void* d_ws, size_t ws_size,
                              hipStream_t stream) {
  char* p = (char*)d_ws;
  auto carve = [&](size_t bytes) -> void* {
    void* r = (void*)p;
    p += (bytes + 255) & ~(size_t)255;
    return r;
  };

  Params P;
  P.X     = (const float*)d_in[0];
  P.E     = (const float*)d_in[1];
  P.nbr   = (const float*)d_in[2];
  P.embW  = (const float*)d_in[3];
  P.embB  = (const float*)d_in[4];
  P.boutW = (const float*)d_in[5];
  P.boutB = (const float*)d_in[6];
  P.qpW   = (const float*)d_in[7];
  P.qpB   = (const float*)d_in[8];
  P.kpW   = (const float*)d_in[9];
  P.kpB   = (const float*)d_in[10];
  P.qoW   = (const float*)d_in[11];
  P.qoB   = (const float*)d_in[12];
  P.koW   = (const float*)d_in[13];
  P.koB   = (const float*)d_in[14];
  P.bpW   = (const float*)d_in[15];
  P.bpB   = (const float*)d_in[16];
  P.bowW  = (const float*)d_in[17];
  P.bowB  = (const float*)d_in[18];
  P.qlnG  = (const float*)d_in[19];
  P.qlnB  = (const float*)d_in[20];
  P.klnG  = (const float*)d_in[21];
  P.klnB  = (const float*)d_in[22];
  P.out   = (float*)d_out;

  P.pkT      = (float*)carve((size_t)4 * 512 * 256 * 4);
  P.rareRow  = (float*)carve((size_t)65536 * 128 * 4);
  P.clsDiff  = (float*)carve((size_t)32 * 4);
  P.rareDiff = (float*)carve((size_t)256 * 256 * 16 * 4);
  P.bar      = (unsigned*)carve(256);

  // Zero the barrier state every launch (stream-ordered; graph-captures as a
  // cheap memset node). Workspace contents are otherwise not guaranteed.
  hipMemsetAsync(P.bar, 0, 256, stream);

  hipLaunchKernelGGL(crakn, dim3(129), dim3(1024), 0, stream, P);
}

// Round 9
// 162.728 us; speedup vs baseline: 5.1935x; 1.0445x over previous
//
#include <hip/hip_runtime.h>

struct Params {
  const float *X, *E, *nbr;
  const float *embW, *embB, *boutW, *boutB;
  const float *qpW, *qpB, *kpW, *kpB, *qoW, *qoB, *koW, *koB;
  const float *bpW, *bpB, *bowW, *bowB;
  const float *qlnG, *qlnB, *klnG, *klnB;
  float *out;
  float *pkT;      // [4][512][256] all-layer transposed keys
  float *clsDiff;  // [4][2][4] class-bias norms from the dedicated bias block
  unsigned *bar;   // grid-barrier state (memset to 0 every launch)
};

__device__ __forceinline__ float mishf(float x) {
  float sp = (x > 20.f) ? x : log1pf(expf(x));
  return x * tanhf(sp);
}

// Function, not macro — a macro param named `w` gets substituted into `acc.w`.
__device__ __forceinline__ void fma4(float4& acc, float s, const float4& v) {
  acc.x = fmaf(s, v.x, acc.x);
  acc.y = fmaf(s, v.y, acc.y);
  acc.z = fmaf(s, v.z, acc.z);
  acc.w = fmaf(s, v.w, acc.w);
}

// NAMED-register 8-deep load batch. An array `float4 wv[8]` goes to SCRATCH:
// SROA runs before unrolling, sees runtime indices, leaves the alloca ->
// every staged load becomes a scratch round-trip (rounds 5/6: 734MB FETCH /
// 392MB WRITE of pure spill traffic). Named SSA values cannot hit scratch.
#define LOAD8(Wp_, J0_, STRIDE_) \
  const float4 w0 = (Wp_)[(size_t)((J0_) + 0) * (STRIDE_)]; \
  const float4 w1 = (Wp_)[(size_t)((J0_) + 1) * (STRIDE_)]; \
  const float4 w2 = (Wp_)[(size_t)((J0_) + 2) * (STRIDE_)]; \
  const float4 w3 = (Wp_)[(size_t)((J0_) + 3) * (STRIDE_)]; \
  const float4 w4 = (Wp_)[(size_t)((J0_) + 4) * (STRIDE_)]; \
  const float4 w5 = (Wp_)[(size_t)((J0_) + 5) * (STRIDE_)]; \
  const float4 w6 = (Wp_)[(size_t)((J0_) + 6) * (STRIDE_)]; \
  const float4 w7 = (Wp_)[(size_t)((J0_) + 7) * (STRIDE_)];

// Hand-rolled single-use grid barrier (state memset to 0 before each launch).
// Regular launch instead of hipLaunchCooperativeKernel (R8: -40us/iter fixed
// cost). Co-residency by construction: 129 blocks, 1 block/CU (LDS > 80KB).
__device__ __forceinline__ void gridBarrier(unsigned* bar, unsigned nblocks) {
  __syncthreads();
  if (threadIdx.x == 0) {
    __threadfence();
    unsigned old = atomicAdd(bar, 1u);
    if (old == nblocks - 1u) {
      atomicExch(bar + 16, 1u);
    } else {
      while (atomicAdd(bar + 16, 0u) == 0u) {
        __builtin_amdgcn_s_sleep(2);
      }
    }
    __threadfence();
  }
  __syncthreads();
}

// Full bias pipe for ONE rare-pair row, one layer. row/drow live in LDS; the
// row evolves in place (layer l -> l+1). The rare chain depends only on the
// pair's distance — NOT on q/k — so each pair runs all 4 layers back-to-back
// with one live row, eliminating the 96MB global rareRow/rareDiff arenas
// (whose per-iteration re-poison was the prime suspect for ~90us of fixed
// score overhead). Cold correctness path: no rare pairs in this data.
__device__ void rare_pipe(float* row, float* drow,
                          const float* __restrict__ Wp, const float* __restrict__ Bp,
                          const float* __restrict__ Wo, const float* __restrict__ Bo,
                          float* smW, float* smS, int t) {
  const int lane = t & 63, wave = t >> 6;
  __syncthreads();                      // row ready / smW free
  { const int o = t & 511, kh = t >> 9;
    const float* Wc = Wp + (kh * 64) * 512 + o;
    const float* rc = row + kh * 64;
    float a = (kh == 0) ? Bp[o] : 0.f;
    #pragma unroll 8
    for (int c = 0; c < 64; ++c) a = fmaf(rc[c], Wc[c * 512], a);
    smW[t] = a; }
  __syncthreads();
  if (t < 512) smS[t] = smW[t] + smW[512 + t];
  __syncthreads();
  if (wave < 4) {
    float e1 = smS[wave * 128 + lane], e2 = smS[wave * 128 + 64 + lane];
    float s = e1 * e1 + e2 * e2;
    #pragma unroll
    for (int sh = 32; sh; sh >>= 1) s += __shfl_xor(s, sh);
    if (lane == 0) drow[wave] = sqrtf(s);
  }
  { const int c = t & 127, ch = t >> 7;
    const float* Woc = Wo + (ch * 64) * 128 + c;
    const float* bc = smS + ch * 64;
    float a = 0.f;
    #pragma unroll 8
    for (int o2 = 0; o2 < 64; ++o2) a = fmaf(bc[o2], Woc[o2 * 128], a);
    smW[t] = a; }
  __syncthreads();
  if (t < 128) {
    float a = Bo[t];
    #pragma unroll
    for (int j = 0; j < 8; ++j) a += smW[t + 128 * j];
    row[t] = mishf(a);
  }
  __syncthreads();
}

// 129 blocks x 1024 threads; ONE grid-wide barrier.
// Blocks 0..127: DUAL-crystal chains (n = 2b, 2b+1) jammed on one weight stream.
// Block 128: the n-independent class-bias chain.
// Hot GEMVs: float4 weight loads along O + 8-deep NAMED-register load batches.
__global__ void __launch_bounds__(1024)
__attribute__((amdgpu_waves_per_eu(4, 4)))
crakn(Params P) {
  const int b = blockIdx.x, t = threadIdx.x;
  const int lane = t & 63, wave = t >> 6;
  const int nA = 2 * b, nB = 2 * b + 1;

  // persistent
  __shared__ __align__(16) float smPQA[2048];         // pq all layers, crystal A
  __shared__ __align__(16) float smPQB[2048];         // crystal B
  __shared__ __align__(16) float smKrA[512], smKrB[512];
  __shared__ __align__(16) float smQA[64], smQB[64], smKqA[64], smKqB[64];
  __shared__ __align__(16) float smNbr[256];
  __shared__ int   smMapA[256], smMapB[256];  // -2 zero-class, -1 gen-class, >=0 rare
  __shared__ float smDiff[32];                // [layer][class][head]
  __shared__ __align__(16) float smPDA[4096], smPDB[4096]; // rare diffs [pair][l][h]
  __shared__ __align__(16) float rowBuf[512]; // bias block: class rows; crystal: E staging
  __shared__ float smPredA, smPredB;
  __shared__ int   smIA[257], smIB[257];
  __shared__ float smDA[256], smDB[256];
  // scratch (total LDS ~111KB -> exactly 1 block/CU, barrier co-residency safe)
  __shared__ __align__(16) float4 smP4A[1024];        // partials (crystal A / class z)
  __shared__ __align__(16) float4 smP4B[1024];        // partials (crystal B / class g)
  __shared__ __align__(16) float smW[1024], smB2[1024], smX2[1024], smY2[1024];
  __shared__ float smH[128];

  if (b == 128) {
    // ================= Dedicated class-bias chain =================
    if (t < 128) {
      float c = (float)t * (1.f / 127.f);
      rowBuf[t] = expf(-127.f * c * c);  // zero class (d == 0)
      rowBuf[128 + t] = 0.f;             // gen class (underflowed)
    }
    __syncthreads();
    for (int l = 0; l < 4; ++l) {
      const float* rowCur = rowBuf + (l & 1) * 256;
      float* rowNxt = rowBuf + ((l + 1) & 1) * 256;
      // bias1 partials: thread = (kc in 0..7) x (o4 in 0..127); 16 K each
      { const int o4 = t & 127, kc = t >> 7;
        const float4* Wf = (const float4*)(P.bpW + (size_t)l * 65536) + (size_t)(kc * 16) * 128 + o4;
        float4 az = {0.f,0.f,0.f,0.f}, ag = {0.f,0.f,0.f,0.f};
        { LOAD8(Wf, 0, 128);
          const int r = kc * 16;
          fma4(az, rowCur[r+0], w0); fma4(ag, rowCur[128+r+0], w0);
          fma4(az, rowCur[r+1], w1); fma4(ag, rowCur[128+r+1], w1);
          fma4(az, rowCur[r+2], w2); fma4(ag, rowCur[128+r+2], w2);
          fma4(az, rowCur[r+3], w3); fma4(ag, rowCur[128+r+3], w3);
          fma4(az, rowCur[r+4], w4); fma4(ag, rowCur[128+r+4], w4);
          fma4(az, rowCur[r+5], w5); fma4(ag, rowCur[128+r+5], w5);
          fma4(az, rowCur[r+6], w6); fma4(ag, rowCur[128+r+6], w6);
          fma4(az, rowCur[r+7], w7); fma4(ag, rowCur[128+r+7], w7);
        }
        { LOAD8(Wf, 8, 128);
          const int r = kc * 16 + 8;
          fma4(az, rowCur[r+0], w0); fma4(ag, rowCur[128+r+0], w0);
          fma4(az, rowCur[r+1], w1); fma4(ag, rowCur[128+r+1], w1);
          fma4(az, rowCur[r+2], w2); fma4(ag, rowCur[128+r+2], w2);
          fma4(az, rowCur[r+3], w3); fma4(ag, rowCur[128+r+3], w3);
          fma4(az, rowCur[r+4], w4); fma4(ag, rowCur[128+r+4], w4);
          fma4(az, rowCur[r+5], w5); fma4(ag, rowCur[128+r+5], w5);
          fma4(az, rowCur[r+6], w6); fma4(ag, rowCur[128+r+6], w6);
          fma4(az, rowCur[r+7], w7); fma4(ag, rowCur[128+r+7], w7);
        }
        smP4A[t] = az; smP4B[t] = ag; }   // idx = kc*128 + o4
      __syncthreads();
      if (t < 512) {
        const float* pa = (const float*)smP4A;
        const float* pb = (const float*)smP4B;
        float bp = P.bpB[l * 512 + t];
        float z = bp, g2 = bp;
        #pragma unroll
        for (int kc = 0; kc < 8; ++kc) { z += pa[kc * 512 + t]; g2 += pb[kc * 512 + t]; }
        smW[t] = z; smB2[t] = g2;
      }
      __syncthreads();
      if (wave < 8) {                     // per-head norms -> global clsDiff
        const int cls = wave >> 2, h = wave & 3;
        const float* arr = cls ? smB2 : smW;
        float e1 = arr[h * 128 + lane], e2 = arr[h * 128 + 64 + lane];
        float s = e1 * e1 + e2 * e2;
        #pragma unroll
        for (int sh = 32; sh; sh >>= 1) s += __shfl_xor(s, sh);
        if (lane == 0) P.clsDiff[(l * 2 + cls) * 4 + h] = sqrtf(s);
      }
      if (l < 3) {
        // bias2 partials: thread = (kc in 0..31) x (o4 in 0..31); 16 K each
        { const int o4 = t & 31, kc = t >> 5;
          const float4* Wf = (const float4*)(P.bowW + (size_t)l * 65536) + (size_t)(kc * 16) * 32 + o4;
          float4 az = {0.f,0.f,0.f,0.f}, ag = {0.f,0.f,0.f,0.f};
          { LOAD8(Wf, 0, 32);
            const int r = kc * 16;
            fma4(az, smW[r+0], w0); fma4(ag, smB2[r+0], w0);
            fma4(az, smW[r+1], w1); fma4(ag, smB2[r+1], w1);
            fma4(az, smW[r+2], w2); fma4(ag, smB2[r+2], w2);
            fma4(az, smW[r+3], w3); fma4(ag, smB2[r+3], w3);
            fma4(az, smW[r+4], w4); fma4(ag, smB2[r+4], w4);
            fma4(az, smW[r+5], w5); fma4(ag, smB2[r+5], w5);
            fma4(az, smW[r+6], w6); fma4(ag, smB2[r+6], w6);
            fma4(az, smW[r+7], w7); fma4(ag, smB2[r+7], w7);
          }
          { LOAD8(Wf, 8, 32);
            const int r = kc * 16 + 8;
            fma4(az, smW[r+0], w0); fma4(ag, smB2[r+0], w0);
            fma4(az, smW[r+1], w1); fma4(ag, smB2[r+1], w1);
            fma4(az, smW[r+2], w2); fma4(ag, smB2[r+2], w2);
            fma4(az, smW[r+3], w3); fma4(ag, smB2[r+3], w3);
            fma4(az, smW[r+4], w4); fma4(ag, smB2[r+4], w4);
            fma4(az, smW[r+5], w5); fma4(ag, smB2[r+5], w5);
            fma4(az, smW[r+6], w6); fma4(ag, smB2[r+6], w6);
            fma4(az, smW[r+7], w7); fma4(ag, smB2[r+7], w7);
          }
          smP4A[t] = az; smP4B[t] = ag; }  // idx = kc*32 + o4
        __syncthreads();
        if (t < 128) {
          const float* pa = (const float*)smP4A;
          const float* pb = (const float*)smP4B;
          float bo = P.bowB[l * 128 + t];
          float sz = 0.f, sg = 0.f;
          #pragma unroll
          for (int kc = 0; kc < 32; ++kc) { sz += pa[kc * 128 + t]; sg += pb[kc * 128 + t]; }
          rowNxt[t] = mishf(sz + bo);
          rowNxt[128 + t] = mishf(sg + bo);
        }
        __syncthreads();
      }
    }
  } else {
    // ================= Phase A: embed / pred0 / distances (dual) =================
    if (t < 256) {
      smX2[t] = P.X[(size_t)nA * 256 + t];
      smY2[t] = P.X[(size_t)nB * 256 + t];
      smNbr[t] = P.nbr[t];
    }
    if (t == 0) { smIA[256] = 0; smIB[256] = 0; }
    __syncthreads();
    { const int d = t & 63, ch = t >> 6;
      const float* W = P.embW + (ch * 16) * 64 + d;
      const float* xrA = smX2 + ch * 16;
      const float* xrB = smY2 + ch * 16;
      float aA = 0.f, aB = 0.f;
      #pragma unroll
      for (int f = 0; f < 16; ++f) {
        float w = W[f * 64];
        aA = fmaf(xrA[f], w, aA);
        aB = fmaf(xrB[f], w, aB);
      }
      smW[t] = aA; smB2[t] = aB; }
    { float pp = 0.f;
      if (t < 256) pp = smX2[t] * P.boutW[t];
      else if (t < 512) pp = smY2[t - 256] * P.boutW[t - 256];
      #pragma unroll
      for (int s = 32; s; s >>= 1) pp += __shfl_xor(pp, s);
      if (t < 512 && lane == 0) smH[wave] = pp; }   // waves 0..3 A, 4..7 B
    __syncthreads();
    if (t < 64) {
      float ndA = P.embB[t], ndB = P.embB[t];
      #pragma unroll
      for (int j = 0; j < 16; ++j) { ndA += smW[t + 64 * j]; ndB += smB2[t + 64 * j]; }
      smQA[t] = ndA; smKqA[t] = ndA;
      smQB[t] = ndB; smKqB[t] = ndB;
    }
    if (t == 0) {
      smPredA = smH[0] + smH[1] + smH[2] + smH[3] + P.boutB[0];
      smPredB = smH[4] + smH[5] + smH[6] + smH[7] + P.boutB[0];
    }
    if (t < 25) {
      ((float4*)rowBuf)[t]         = ((const float4*)(P.E + (size_t)nA * 100))[t];
      ((float4*)(rowBuf + 128))[t] = ((const float4*)(P.E + (size_t)nB * 100))[t];
    }
    __syncthreads();
    if (t < 512) {                      // distances: t<256 crystal A, else B
      const int m = t & 255, cr = t >> 8;
      const float4* em = (const float4*)(P.E + (size_t)m * 100);
      const float4* en = (const float4*)(cr ? (rowBuf + 128) : rowBuf);
      float sq = 0.f;
      #pragma unroll 5
      for (int jj = 0; jj < 25; ++jj) {
        float4 a = en[jj], c = em[jj];
        float dx = a.x - c.x, dy = a.y - c.y, dz = a.z - c.z, dw = a.w - c.w;
        sq += dx * dx + dy * dy + dz * dz + dw * dw;
      }
      float dd = (sq > 0.f) ? sqrtf(sq) : 0.f;
      // exp(-127*(d-c)^2) fp32-underflows to exactly 0 for d>=1.905.
      int mv;
      if (dd == 0.f) mv = -2;
      else if (dd < 1.905f) {
        int* sI = cr ? smIB : smIA;
        float* sD = cr ? smDB : smDA;
        int i = atomicAdd(&sI[256], 1);
        sI[i] = m; sD[i] = dd;
        mv = i;
      } else mv = -1;
      (cr ? smMapB : smMapA)[m] = mv;
    }
    __syncthreads();
    // ---- rare-pair pipes: each pair runs ALL 4 layers with one LDS row ----
    { int cntA = smIA[256]; if (cntA > 256) cntA = 256;
      int cntB = smIB[256]; if (cntB > 256) cntB = 256;
      if (cntA + cntB > 0) {            // cold path (none in this data)
        for (int i = 0; i < cntA; ++i) {
          if (t < 128) {
            float dd = smDA[i] - (float)t * (1.f / 127.f);
            smY2[t] = expf(-127.f * dd * dd);
          }
          for (int l = 0; l < 4; ++l)
            rare_pipe(smY2, smPDA + i * 16 + l * 4,
                      P.bpW + (size_t)l * 65536, P.bpB + l * 512,
                      P.bowW + (size_t)l * 65536, P.bowB + l * 128, smW, smX2, t);
        }
        for (int i = 0; i < cntB; ++i) {
          if (t < 128) {
            float dd = smDB[i] - (float)t * (1.f / 127.f);
            smY2[t] = expf(-127.f * dd * dd);
          }
          for (int l = 0; l < 4; ++l)
            rare_pipe(smY2, smPDB + i * 16 + l * 4,
                      P.bpW + (size_t)l * 65536, P.bpB + l * 512,
                      P.bowW + (size_t)l * 65536, P.bowB + l * 128, smW, smX2, t);
        }
      } }
    __syncthreads();

    // ============ Phase 1: dual q/k chains, float4 + named-reg batches ============
    for (int l = 0; l < 4; ++l) {
      // --- S0 partials: thread = (g, kc in 0..3, o4 in 0..127); 16 K each ---
      { const int g = t >> 9, u = t & 511;
        const int o4 = u & 127, kc = u >> 7;
        const float4* Wf = (const float4*)((g ? P.kpW : P.qpW) + (size_t)l * 32768)
                         + (size_t)(kc * 16) * 128 + o4;
        const float* xa = g ? smKqA : smQA;
        const float* xb = g ? smKqB : smQB;
        float4 aA = {0.f,0.f,0.f,0.f}, aB = {0.f,0.f,0.f,0.f};
        { LOAD8(Wf, 0, 128);
          const int r = kc * 16;
          fma4(aA, xa[r+0], w0); fma4(aB, xb[r+0], w0);
          fma4(aA, xa[r+1], w1); fma4(aB, xb[r+1], w1);
          fma4(aA, xa[r+2], w2); fma4(aB, xb[r+2], w2);
          fma4(aA, xa[r+3], w3); fma4(aB, xb[r+3], w3);
          fma4(aA, xa[r+4], w4); fma4(aB, xb[r+4], w4);
          fma4(aA, xa[r+5], w5); fma4(aB, xb[r+5], w5);
          fma4(aA, xa[r+6], w6); fma4(aB, xb[r+6], w6);
          fma4(aA, xa[r+7], w7); fma4(aB, xb[r+7], w7);
        }
        { LOAD8(Wf, 8, 128);
          const int r = kc * 16 + 8;
          fma4(aA, xa[r+0], w0); fma4(aB, xb[r+0], w0);
          fma4(aA, xa[r+1], w1); fma4(aB, xb[r+1], w1);
          fma4(aA, xa[r+2], w2); fma4(aB, xb[r+2], w2);
          fma4(aA, xa[r+3], w3); fma4(aB, xb[r+3], w3);
          fma4(aA, xa[r+4], w4); fma4(aB, xb[r+4], w4);
          fma4(aA, xa[r+5], w5); fma4(aB, xb[r+5], w5);
          fma4(aA, xa[r+6], w6); fma4(aB, xb[r+6], w6);
          fma4(aA, xa[r+7], w7); fma4(aB, xb[r+7], w7);
        }
        smP4A[t] = aA; smP4B[t] = aB; }   // idx = g*512 + kc*128 + o4
      __syncthreads();
      // --- S0 reduce: output o per (g); write pq/pk + pkT ---
      { const int g = t >> 9, o = t & 511;
        const float* pa = (const float*)smP4A + g * 2048;
        const float* pb = (const float*)smP4B + g * 2048;
        float b0 = (g ? P.kpB : P.qpB)[l * 512 + o];
        float vA = b0 + pa[o] + pa[512 + o] + pa[1024 + o] + pa[1536 + o];
        float vB = b0 + pb[o] + pb[512 + o] + pb[1024 + o] + pb[1536 + o];
        if (g) {
          smKrA[o] = vA; smKrB[o] = vB;
          float2 st; st.x = vA; st.y = vB;
          *(float2*)(P.pkT + (size_t)l * 131072 + (size_t)o * 256 + nA) = st;
        } else { smPQA[l * 512 + o] = vA; smPQB[l * 512 + o] = vB; } }
      __syncthreads();
      if (l < 3) {
        // --- S2 partials: thread = (g, kc in 0..31, o4 in 0..15); 16 K each ---
        // pi(r) = ((r&3)<<7)|(r>>2); r = kc*16+off -> pi = ((off&3)<<7)|(kc*4+(off>>2))
        { const int g = t >> 9, u = t & 511;
          const int o4 = u & 15, kc = u >> 4;
          const float4* Wf = (const float4*)((g ? P.koW : P.qoW) + (size_t)l * 32768)
                           + (size_t)(kc * 16) * 16 + o4;
          const float* prA = g ? smKrA : (smPQA + l * 512);
          const float* prB = g ? smKrB : (smPQB + l * 512);
          const int pb0 = kc * 4;
          float4 aA = {0.f,0.f,0.f,0.f}, aB = {0.f,0.f,0.f,0.f};
          { LOAD8(Wf, 0, 16);
            fma4(aA, prA[pb0 + 0],       w0); fma4(aB, prB[pb0 + 0],       w0);
            fma4(aA, prA[128 + pb0],     w1); fma4(aB, prB[128 + pb0],     w1);
            fma4(aA, prA[256 + pb0],     w2); fma4(aB, prB[256 + pb0],     w2);
            fma4(aA, prA[384 + pb0],     w3); fma4(aB, prB[384 + pb0],     w3);
            fma4(aA, prA[pb0 + 1],       w4); fma4(aB, prB[pb0 + 1],       w4);
            fma4(aA, prA[128 + pb0 + 1], w5); fma4(aB, prB[128 + pb0 + 1], w5);
            fma4(aA, prA[256 + pb0 + 1], w6); fma4(aB, prB[256 + pb0 + 1], w6);
            fma4(aA, prA[384 + pb0 + 1], w7); fma4(aB, prB[384 + pb0 + 1], w7);
          }
          { LOAD8(Wf, 8, 16);
            fma4(aA, prA[pb0 + 2],       w0); fma4(aB, prB[pb0 + 2],       w0);
            fma4(aA, prA[128 + pb0 + 2], w1); fma4(aB, prB[128 + pb0 + 2], w1);
            fma4(aA, prA[256 + pb0 + 2], w2); fma4(aB, prB[256 + pb0 + 2], w2);
            fma4(aA, prA[384 + pb0 + 2], w3); fma4(aB, prB[384 + pb0 + 2], w3);
            fma4(aA, prA[pb0 + 3],       w4); fma4(aB, prB[pb0 + 3],       w4);
            fma4(aA, prA[128 + pb0 + 3], w5); fma4(aB, prB[128 + pb0 + 3], w5);
            fma4(aA, prA[256 + pb0 + 3], w6); fma4(aB, prB[256 + pb0 + 3], w6);
            fma4(aA, prA[384 + pb0 + 3], w7); fma4(aB, prB[384 + pb0 + 3], w7);
          }
          smP4A[t] = aA; smP4B[t] = aB; }  // idx = g*512 + kc*16 + o4
        __syncthreads();
        // --- S3: reduce + mish + LN (waves 0,1 / 8,9 handle A,B) ---
        { const int g = t >> 9, u = t & 511;
          if (u < 128) {
            const int cr = u >> 6, uu = u & 63;
            const float* src = (const float*)(cr ? smP4B : smP4A) + g * 2048;
            float acc = (g ? P.koB : P.qoB)[l * 64 + uu];
            #pragma unroll
            for (int kc = 0; kc < 32; ++kc) acc += src[kc * 64 + uu];
            float* x = g ? (cr ? smKqB : smKqA) : (cr ? smQB : smQA);
            float xv = x[uu] + mishf(acc);
            float mean = xv;
            #pragma unroll
            for (int s = 32; s; s >>= 1) mean += __shfl_xor(mean, s);
            mean *= (1.f / 64.f);
            float dv = xv - mean, var = dv * dv;
            #pragma unroll
            for (int s = 32; s; s >>= 1) var += __shfl_xor(var, s);
            var *= (1.f / 64.f);
            const float* G  = (g ? P.klnG : P.qlnG) + l * 64;
            const float* Bb = (g ? P.klnB : P.qlnB) + l * 64;
            x[uu] = dv * rsqrtf(var + 1e-5f) * G[uu] + Bb[uu];
          } }
        __syncthreads();
      }
    }
  }

  gridBarrier(P.bar, 129);   // the ONLY grid-wide sync: pkT + clsDiff now visible
  if (b >= 128) return;

  // ====== Phase 2: ALL (layer, head) attention, both crystals jammed ======
  if (t < 32) smDiff[t] = P.clsDiff[t];
  __syncthreads();
  {
    const int l = t >> 8, h = (t >> 6) & 3, mq = lane;   // wave = (l,h), lane = mq
    const float* qvA = smPQA + l * 512 + h * 128;
    const float* qvB = smPQB + l * 512 + h * 128;
    const float4* pt4 = (const float4*)P.pkT + (size_t)l * 32768 + (size_t)h * 128 * 64 + mq;
    float4 dA = {0.f, 0.f, 0.f, 0.f}, dB = {0.f, 0.f, 0.f, 0.f};
    for (int jb = 0; jb < 16; ++jb) {
      const int j0 = jb * 8;
      LOAD8(pt4, j0, 64);
      fma4(dA, qvA[j0+0], w0); fma4(dB, qvB[j0+0], w0);
      fma4(dA, qvA[j0+1], w1); fma4(dB, qvB[j0+1], w1);
      fma4(dA, qvA[j0+2], w2); fma4(dB, qvB[j0+2], w2);
      fma4(dA, qvA[j0+3], w3); fma4(dB, qvB[j0+3], w3);
      fma4(dA, qvA[j0+4], w4); fma4(dB, qvB[j0+4], w4);
      fma4(dA, qvA[j0+5], w5); fma4(dB, qvB[j0+5], w5);
      fma4(dA, qvA[j0+6], w6); fma4(dB, qvB[j0+6], w6);
      fma4(dA, qvA[j0+7], w7); fma4(dB, qvB[j0+7], w7);
    }
    auto epi = [&](const float4& dot, const int* sMap, const float* sPD, int nn, float* oH) {
      float dArr[4] = {dot.x, dot.y, dot.z, dot.w};
      float lg[4], nb[4];
      int self = -1;
      #pragma unroll
      for (int i = 0; i < 4; ++i) {
        const int m = mq * 4 + i;
        const int cls = sMap[m];
        const float bd = (cls == -2) ? smDiff[(l * 2 + 0) * 4 + h]
                       : (cls == -1) ? smDiff[(l * 2 + 1) * 4 + h]
                       : sPD[cls * 16 + l * 4 + h];
        lg[i] = dArr[i] * 0.08838834764831845f + bd;   // 1/sqrt(128)
        nb[i] = smNbr[m];
        if (m == nn) { self = i; nb[i] = 0.f; }
      }
      float wm = fmaxf(fmaxf(lg[0], lg[1]), fmaxf(lg[2], lg[3]));
      #pragma unroll
      for (int s = 32; s; s >>= 1) wm = fmaxf(wm, __shfl_xor(wm, s));
      float sA = 0.f, sB = 0.f, sD = 0.f;
      #pragma unroll
      for (int i = 0; i < 4; ++i) {
        float e = expf(lg[i] - wm);
        sD += e;
        sA = fmaf(e, nb[i], sA);
        if (i == self) sB = e;
      }
      #pragma unroll
      for (int s = 32; s; s >>= 1) {
        sA += __shfl_xor(sA, s); sB += __shfl_xor(sB, s); sD += __shfl_xor(sD, s);
      }
      if (lane == 0) { oH[wave] = sA; oH[16 + wave] = sB; oH[32 + wave] = sD; }
    };
    epi(dA, smMapA, smPDA, nA, smH);
    epi(dB, smMapB, smPDB, nB, smH + 48);
  }
  __syncthreads();
  if (t == 0 || t == 64) {              // serial pred chains (A on wave0, B on wave1)
    const float* H = (t == 0) ? smH : smH + 48;
    float p = (t == 0) ? smPredA : smPredB;
    #pragma unroll
    for (int l = 0; l < 4; ++l) {
      float np = 0.f;
      #pragma unroll
      for (int h = 0; h < 4; ++h) {
        const int w = l * 4 + h;
        np += 0.25f * ((H[w] + H[16 + w] * p) / H[32 + w]);
      }
      p = np;
    }
    P.out[(t == 0) ? nA : nB] = p;
  }
}

// ---------------------------------------------------------------------------
extern "C" void kernel_launch(void* const* d_in, const int* in_sizes, int n_in,
                              void* d_out, int out_size, void* d_ws, size_t ws_size,
                              hipStream_t stream) {
  char* p = (char*)d_ws;
  auto carve = [&](size_t bytes) -> void* {
    void* r = (void*)p;
    p += (bytes + 255) & ~(size_t)255;
    return r;
  };

  Params P;
  P.X     = (const float*)d_in[0];
  P.E     = (const float*)d_in[1];
  P.nbr   = (const float*)d_in[2];
  P.embW  = (const float*)d_in[3];
  P.embB  = (const float*)d_in[4];
  P.boutW = (const float*)d_in[5];
  P.boutB = (const float*)d_in[6];
  P.qpW   = (const float*)d_in[7];
  P.qpB   = (const float*)d_in[8];
  P.kpW   = (const float*)d_in[9];
  P.kpB   = (const float*)d_in[10];
  P.qoW   = (const float*)d_in[11];
  P.qoB   = (const float*)d_in[12];
  P.koW   = (const float*)d_in[13];
  P.koB   = (const float*)d_in[14];
  P.bpW   = (const float*)d_in[15];
  P.bpB   = (const float*)d_in[16];
  P.bowW  = (const float*)d_in[17];
  P.bowB  = (const float*)d_in[18];
  P.qlnG  = (const float*)d_in[19];
  P.qlnB  = (const float*)d_in[20];
  P.klnG  = (const float*)d_in[21];
  P.klnB  = (const float*)d_in[22];
  P.out   = (float*)d_out;

  // Workspace: 2.1 MB total (was 96 MB — rare-pair arenas moved to LDS; the
  // harness re-poisons ws every iteration, so ws size is per-iteration cost).
  P.pkT     = (float*)carve((size_t)4 * 512 * 256 * 4);
  P.clsDiff = (float*)carve((size_t)32 * 4);
  P.bar     = (unsigned*)carve(256);

  // Zero the barrier state every launch (stream-ordered; graph-captures as a
  // cheap memset node). Workspace contents are otherwise not guaranteed.
  hipMemsetAsync(P.bar, 0, 256, stream);

  hipLaunchKernelGGL(crakn, dim3(129), dim3(1024), 0, stream, P);
}